// Round 1
// baseline (508.961 us; speedup 1.0000x reference)
//
#include <hip/hip_runtime.h>
#include <math.h>

#define BB   8
#define HH   8
#define DDIM 64
#define NN   1024
#define HID  512
#define COUT 320

typedef float4 f4;

__device__ __forceinline__ void fma4x4(float acc[4][4], const float a[4], const float b[4]) {
#pragma unroll
    for (int r = 0; r < 4; ++r)
#pragma unroll
        for (int c = 0; c < 4; ++c)
            acc[r][c] = fmaf(a[r], b[c], acc[r][c]);
}

// ---------------------------------------------------------------------------
// QKV projection: dst[b,h,i,d] = scale * sum_c W[o,c] * X[b,c,i],  o = h*64+d
// grid (NN/64, OUT/64, BB), 256 threads. o0 < HID -> dst0 (Q or K); else dst1 (V).
// ---------------------------------------------------------------------------
template<int CIN>
__global__ __launch_bounds__(256)
void proj_kernel(const float* __restrict__ X, const float* __restrict__ W,
                 float* __restrict__ dst0, float* __restrict__ dst1, float scale)
{
    const int i0 = blockIdx.x * 64;
    const int o0 = blockIdx.y * 64;
    const int b  = blockIdx.z;
    const int t  = threadIdx.x;
    const int tx = t & 15, ty = t >> 4;

    __shared__ float Ws[16][68];   // [kk][o_local]
    __shared__ float Xs[16][68];   // [kk][i_local]

    float acc[4][4] = {};          // [i_sub][o_sub]

    const float* Xb = X + (size_t)b * CIN * NN;
    const int wo = t >> 2, wk = (t & 3) << 2;
    const int xk = t >> 4, xi = (t & 15) << 2;

    for (int k0 = 0; k0 < CIN; k0 += 16) {
        const f4 w4 = *(const f4*)&W[(size_t)(o0 + wo) * CIN + (k0 + wk)];
        const f4 x4 = *(const f4*)&Xb[(size_t)(k0 + xk) * NN + (i0 + xi)];
        Ws[wk + 0][wo] = w4.x;
        Ws[wk + 1][wo] = w4.y;
        Ws[wk + 2][wo] = w4.z;
        Ws[wk + 3][wo] = w4.w;
        *(f4*)&Xs[xk][xi] = x4;
        __syncthreads();
#pragma unroll
        for (int kk = 0; kk < 16; ++kk) {
            float a[4], bo[4];
            *(f4*)a  = *(const f4*)&Xs[kk][ty << 2];
            *(f4*)bo = *(const f4*)&Ws[kk][tx << 2];
            fma4x4(acc, a, bo);
        }
        __syncthreads();
    }

    float* dst; int h;
    if (o0 < HID) { dst = dst0; h = o0 >> 6; }
    else          { dst = dst1; h = (o0 - HID) >> 6; }
    const size_t rowbase = (size_t)(b * HH + h) * NN + i0 + (ty << 2);
#pragma unroll
    for (int r = 0; r < 4; ++r) {
        f4 v;
        v.x = acc[r][0] * scale;
        v.y = acc[r][1] * scale;
        v.z = acc[r][2] * scale;
        v.w = acc[r][3] * scale;
        *(f4*)&dst[(rowbase + r) * DDIM + (tx << 2)] = v;
    }
}

// ---------------------------------------------------------------------------
// Flash attention (fp32). Q pre-scaled. Q,K,V,O all [b*h][n][d].
// grid (NN/64, HH, BB), 256 threads. Each block: 64 query rows.
// ---------------------------------------------------------------------------
__global__ __launch_bounds__(256)
void attn_kernel(const float* __restrict__ Q, const float* __restrict__ K,
                 const float* __restrict__ V, float* __restrict__ O)
{
    const int i0 = blockIdx.x * 64;
    const int bh = blockIdx.z * HH + blockIdx.y;
    const int t  = threadIdx.x;
    const int tx = t & 15, ty = t >> 4;

    __shared__ float Qt[64][68];     // [d][i]   (transposed)
    __shared__ float KtPs[64][68];   // K as [d][j]; reused as P [i][j]
    __shared__ float Vs[64][68];     // [j][d]

    // load Q tile transposed: Qt[d][i]
    const int lj = t >> 2;           // 0..63 row
    const int ld = (t & 3) << 2;     // 0,4,8,12
    {
        const float* qp = &Q[((size_t)bh * NN + i0 + lj) * DDIM + ld];
#pragma unroll
        for (int p = 0; p < 4; ++p) {
            const f4 q4 = *(const f4*)&qp[p * 16];
            Qt[ld + p * 16 + 0][lj] = q4.x;
            Qt[ld + p * 16 + 1][lj] = q4.y;
            Qt[ld + p * 16 + 2][lj] = q4.z;
            Qt[ld + p * 16 + 3][lj] = q4.w;
        }
    }

    float m[4], l[4], o[4][4];
#pragma unroll
    for (int r = 0; r < 4; ++r) {
        m[r] = -INFINITY; l[r] = 0.f;
#pragma unroll
        for (int c = 0; c < 4; ++c) o[r][c] = 0.f;
    }

    for (int j0 = 0; j0 < NN; j0 += 64) {
        const float* kp = &K[((size_t)bh * NN + j0 + lj) * DDIM + ld];
        const float* vp = &V[((size_t)bh * NN + j0 + lj) * DDIM + ld];
        __syncthreads();   // previous iteration done reading KtPs/Vs
#pragma unroll
        for (int p = 0; p < 4; ++p) {
            const f4 k4 = *(const f4*)&kp[p * 16];
            KtPs[ld + p * 16 + 0][lj] = k4.x;
            KtPs[ld + p * 16 + 1][lj] = k4.y;
            KtPs[ld + p * 16 + 2][lj] = k4.z;
            KtPs[ld + p * 16 + 3][lj] = k4.w;
            const f4 v4 = *(const f4*)&vp[p * 16];
            *(f4*)&Vs[lj][ld + p * 16] = v4;
        }
        __syncthreads();

        // S = Q K^T : rows i = 4*ty+r, cols j = 4*tx+c
        float s[4][4] = {};
#pragma unroll 8
        for (int d = 0; d < 64; ++d) {
            float qa[4], kb[4];
            *(f4*)qa = *(const f4*)&Qt[d][ty << 2];
            *(f4*)kb = *(const f4*)&KtPs[d][tx << 2];
            fma4x4(s, qa, kb);
        }

        // online softmax over j (reduce across the 16 tx lanes of this row group)
#pragma unroll
        for (int r = 0; r < 4; ++r) {
            float rm = fmaxf(fmaxf(s[r][0], s[r][1]), fmaxf(s[r][2], s[r][3]));
            rm = fmaxf(rm, __shfl_xor(rm, 1));
            rm = fmaxf(rm, __shfl_xor(rm, 2));
            rm = fmaxf(rm, __shfl_xor(rm, 4));
            rm = fmaxf(rm, __shfl_xor(rm, 8));
            const float mt   = fmaxf(m[r], rm);
            const float corr = expf(m[r] - mt);
            float sum = 0.f;
#pragma unroll
            for (int c = 0; c < 4; ++c) { s[r][c] = expf(s[r][c] - mt); sum += s[r][c]; }
            sum += __shfl_xor(sum, 1);
            sum += __shfl_xor(sum, 2);
            sum += __shfl_xor(sum, 4);
            sum += __shfl_xor(sum, 8);
            l[r] = l[r] * corr + sum;
            m[r] = mt;
#pragma unroll
            for (int c = 0; c < 4; ++c) o[r][c] *= corr;
        }

        __syncthreads();   // everyone done reading KtPs as K
        // write P tile (natural [i][j]) into KtPs
#pragma unroll
        for (int r = 0; r < 4; ++r) {
            f4 pv;
            pv.x = s[r][0]; pv.y = s[r][1]; pv.z = s[r][2]; pv.w = s[r][3];
            *(f4*)&KtPs[(ty << 2) + r][tx << 2] = pv;
        }
        __syncthreads();

        // O += P @ V : o[r][c] over d-cols 4*tx+c
#pragma unroll 4
        for (int j = 0; j < 64; j += 4) {
            float p0[4], p1[4], p2[4], p3[4];
            *(f4*)p0 = *(const f4*)&KtPs[(ty << 2) + 0][j];
            *(f4*)p1 = *(const f4*)&KtPs[(ty << 2) + 1][j];
            *(f4*)p2 = *(const f4*)&KtPs[(ty << 2) + 2][j];
            *(f4*)p3 = *(const f4*)&KtPs[(ty << 2) + 3][j];
#pragma unroll
            for (int u = 0; u < 4; ++u) {
                float vv[4];
                *(f4*)vv = *(const f4*)&Vs[j + u][tx << 2];
#pragma unroll
                for (int c = 0; c < 4; ++c) {
                    o[0][c] = fmaf(p0[u], vv[c], o[0][c]);
                    o[1][c] = fmaf(p1[u], vv[c], o[1][c]);
                    o[2][c] = fmaf(p2[u], vv[c], o[2][c]);
                    o[3][c] = fmaf(p3[u], vv[c], o[3][c]);
                }
            }
        }
    }

    const size_t obase = (size_t)bh * NN + i0 + (ty << 2);
#pragma unroll
    for (int r = 0; r < 4; ++r) {
        const float inv = 1.0f / l[r];
        f4 v;
        v.x = o[r][0] * inv;
        v.y = o[r][1] * inv;
        v.z = o[r][2] * inv;
        v.w = o[r][3] * inv;
        *(f4*)&O[(obase + r) * DDIM + (tx << 2)] = v;
    }
}

// ---------------------------------------------------------------------------
// out[b,o,i] = sum_c Wout[o,c] * Obuf[b, c/64, i, c%64]
// grid (NN/64, COUT/64=5, BB), 256 threads
// ---------------------------------------------------------------------------
__global__ __launch_bounds__(256)
void outproj_kernel(const float* __restrict__ Obuf, const float* __restrict__ W,
                    float* __restrict__ out)
{
    const int i0 = blockIdx.x * 64;
    const int o0 = blockIdx.y * 64;
    const int b  = blockIdx.z;
    const int t  = threadIdx.x;
    const int tx = t & 15, ty = t >> 4;

    __shared__ float Ws[16][68];   // [kk][o_local]
    __shared__ float Xs[16][68];   // [kk][i_local]

    float acc[4][4] = {};          // [o_sub][i_sub]

    const int wo = t >> 2, wk = (t & 3) << 2;
    const int xi = t >> 2, xd = (t & 3) << 2;

    for (int k0 = 0; k0 < HID; k0 += 16) {
        const f4 w4 = *(const f4*)&W[(size_t)(o0 + wo) * HID + (k0 + wk)];
        const int h  = k0 >> 6;
        const int db = (k0 & 63) + xd;
        const f4 x4 = *(const f4*)&Obuf[((size_t)(b * HH + h) * NN + i0 + xi) * DDIM + db];
        Ws[wk + 0][wo] = w4.x;
        Ws[wk + 1][wo] = w4.y;
        Ws[wk + 2][wo] = w4.z;
        Ws[wk + 3][wo] = w4.w;
        Xs[xd + 0][xi] = x4.x;
        Xs[xd + 1][xi] = x4.y;
        Xs[xd + 2][xi] = x4.z;
        Xs[xd + 3][xi] = x4.w;
        __syncthreads();
#pragma unroll
        for (int kk = 0; kk < 16; ++kk) {
            float a[4], xv[4];
            *(f4*)a  = *(const f4*)&Ws[kk][ty << 2];   // o
            *(f4*)xv = *(const f4*)&Xs[kk][tx << 2];   // i
            fma4x4(acc, a, xv);
        }
        __syncthreads();
    }

#pragma unroll
    for (int r = 0; r < 4; ++r) {
        f4 v;
        v.x = acc[r][0]; v.y = acc[r][1]; v.z = acc[r][2]; v.w = acc[r][3];
        *(f4*)&out[((size_t)b * COUT + o0 + (ty << 2) + r) * NN + i0 + (tx << 2)] = v;
    }
}

// ---------------------------------------------------------------------------
extern "C" void kernel_launch(void* const* d_in, const int* in_sizes, int n_in,
                              void* d_out, int out_size, void* d_ws, size_t ws_size,
                              hipStream_t stream)
{
    const float* x_q   = (const float*)d_in[0];
    const float* x_kv  = (const float*)d_in[1];
    const float* w_q   = (const float*)d_in[2];
    const float* w_kv  = (const float*)d_in[3];
    const float* w_out = (const float*)d_in[4];
    float* out = (float*)d_out;

    const size_t buf = (size_t)BB * HID * NN;   // 4.19M floats each
    float* Q = (float*)d_ws;
    float* K = Q + buf;
    float* V = K + buf;
    float* O = V + buf;

    const float scale = 0.125f;   // 64^-0.5

    dim3 blk(256);
    proj_kernel<320><<<dim3(16,  8, 8), blk, 0, stream>>>(x_q,  w_q,  Q, nullptr, scale);
    proj_kernel<640><<<dim3(16, 16, 8), blk, 0, stream>>>(x_kv, w_kv, K, V,       1.0f);
    attn_kernel<<<dim3(16, 8, 8), blk, 0, stream>>>(Q, K, V, O);
    outproj_kernel<<<dim3(16, 5, 8), blk, 0, stream>>>(O, w_out, out);
}

// Round 2
// 359.822 us; speedup vs baseline: 1.4145x; 1.4145x over previous
//
#include <hip/hip_runtime.h>
#include <math.h>

#define BB   8
#define HH   8
#define DDIM 64
#define NN   1024
#define HID  512
#define COUT 320

typedef float4 f4;
typedef __bf16 bf16;
typedef __attribute__((ext_vector_type(8))) __bf16 bf16x8;
typedef __attribute__((ext_vector_type(4))) __bf16 bf16x4;
typedef __attribute__((ext_vector_type(4))) float f32x4;

#define MFMA16(a,b,c) __builtin_amdgcn_mfma_f32_16x16x32_bf16((a),(b),(c),0,0,0)

__device__ __forceinline__ void fma4x4(float acc[4][4], const float a[4], const float b[4]) {
#pragma unroll
    for (int r = 0; r < 4; ++r)
#pragma unroll
        for (int c = 0; c < 4; ++c)
            acc[r][c] = fmaf(a[r], b[c], acc[r][c]);
}

// ---------------------------------------------------------------------------
// Projection producing split-bf16 (hi/lo) in [b,h,n,d] layout.
// dsthi/dstlo[bh*1024*64 ...]. o0 = blockIdx.y*64 selects head h = o0>>6.
// ---------------------------------------------------------------------------
template<int CIN>
__global__ __launch_bounds__(256)
void proj_split_kernel(const float* __restrict__ X, const float* __restrict__ W,
                       bf16* __restrict__ Dhi, bf16* __restrict__ Dlo, float scale)
{
    const int i0 = blockIdx.x * 64;
    const int o0 = blockIdx.y * 64;
    const int b  = blockIdx.z;
    const int t  = threadIdx.x;
    const int tx = t & 15, ty = t >> 4;

    __shared__ float Ws[16][68];
    __shared__ float Xs[16][68];

    float acc[4][4] = {};          // [i_sub][o_sub]

    const float* Xb = X + (size_t)b * CIN * NN;
    const int wo = t >> 2, wk = (t & 3) << 2;
    const int xk = t >> 4, xi = (t & 15) << 2;

    for (int k0 = 0; k0 < CIN; k0 += 16) {
        const f4 w4 = *(const f4*)&W[(size_t)(o0 + wo) * CIN + (k0 + wk)];
        const f4 x4 = *(const f4*)&Xb[(size_t)(k0 + xk) * NN + (i0 + xi)];
        Ws[wk + 0][wo] = w4.x;
        Ws[wk + 1][wo] = w4.y;
        Ws[wk + 2][wo] = w4.z;
        Ws[wk + 3][wo] = w4.w;
        *(f4*)&Xs[xk][xi] = x4;
        __syncthreads();
#pragma unroll
        for (int kk = 0; kk < 16; ++kk) {
            float a[4], bo[4];
            *(f4*)a  = *(const f4*)&Xs[kk][ty << 2];
            *(f4*)bo = *(const f4*)&Ws[kk][tx << 2];
            fma4x4(acc, a, bo);
        }
        __syncthreads();
    }

    const int h = o0 >> 6;
    const size_t rowbase = (size_t)(b * HH + h) * NN + i0 + (ty << 2);
#pragma unroll
    for (int r = 0; r < 4; ++r) {
        bf16x4 hv, lv;
#pragma unroll
        for (int c = 0; c < 4; ++c) {
            float v = acc[r][c] * scale;
            bf16 hb = (bf16)v;
            hv[c] = hb;
            lv[c] = (bf16)(v - (float)hb);
        }
        const size_t off = (rowbase + r) * DDIM + (tx << 2);
        *(bf16x4*)(Dhi + off) = hv;
        *(bf16x4*)(Dlo + off) = lv;
    }
}

// ---------------------------------------------------------------------------
// V projection writing transposed bf16: Vt[bh*64 + d][n]
// W is pre-offset to the V rows. o0 = blockIdx.y*64, h = o0>>6, d = o_local.
// ---------------------------------------------------------------------------
template<int CIN>
__global__ __launch_bounds__(256)
void proj_vt_kernel(const float* __restrict__ X, const float* __restrict__ W,
                    bf16* __restrict__ Vt)
{
    const int i0 = blockIdx.x * 64;
    const int o0 = blockIdx.y * 64;
    const int b  = blockIdx.z;
    const int t  = threadIdx.x;
    const int tx = t & 15, ty = t >> 4;

    __shared__ float Ws[16][68];
    __shared__ float Xs[16][68];

    float acc[4][4] = {};          // [i_sub][o_sub]

    const float* Xb = X + (size_t)b * CIN * NN;
    const int wo = t >> 2, wk = (t & 3) << 2;
    const int xk = t >> 4, xi = (t & 15) << 2;

    for (int k0 = 0; k0 < CIN; k0 += 16) {
        const f4 w4 = *(const f4*)&W[(size_t)(o0 + wo) * CIN + (k0 + wk)];
        const f4 x4 = *(const f4*)&Xb[(size_t)(k0 + xk) * NN + (i0 + xi)];
        Ws[wk + 0][wo] = w4.x;
        Ws[wk + 1][wo] = w4.y;
        Ws[wk + 2][wo] = w4.z;
        Ws[wk + 3][wo] = w4.w;
        *(f4*)&Xs[xk][xi] = x4;
        __syncthreads();
#pragma unroll
        for (int kk = 0; kk < 16; ++kk) {
            float a[4], bo[4];
            *(f4*)a  = *(const f4*)&Xs[kk][ty << 2];
            *(f4*)bo = *(const f4*)&Ws[kk][tx << 2];
            fma4x4(acc, a, bo);
        }
        __syncthreads();
    }

    const int h = o0 >> 6;
    const int bh = b * HH + h;
#pragma unroll
    for (int c = 0; c < 4; ++c) {
        const int d = (tx << 2) + c;
        bf16x4 pv;
#pragma unroll
        for (int r = 0; r < 4; ++r) pv[r] = (bf16)acc[r][c];
        *(bf16x4*)(Vt + ((size_t)(bh * DDIM + d) << 10) + i0 + (ty << 2)) = pv;
    }
}

// ---------------------------------------------------------------------------
// MFMA flash attention.
// Q,K: split bf16 hi/lo [bh][n][d]; Vt: bf16 [bh][d][n]; O: f32 [b][512][n].
// grid (16, HH, BB), 256 threads = 4 waves; wave w handles q rows i0+w*16..+15.
// Computes St = K·Q^T (16x16x32 MFMA, 3-term split), lane-local online softmax
// (lane's 16 St values share q = lane&15), P -> per-wave LDS, Ot = Vt·Pt.
// LDS K/Vt tiles are chunk-XOR swizzled: chunk' = chunk ^ (row&7).
// ---------------------------------------------------------------------------
__global__ __launch_bounds__(256)
void attn_kernel(const bf16* __restrict__ Qhi, const bf16* __restrict__ Qlo,
                 const bf16* __restrict__ Khi, const bf16* __restrict__ Klo,
                 const bf16* __restrict__ Vt,  float* __restrict__ O)
{
    const int i0 = blockIdx.x * 64;
    const int bh = blockIdx.z * HH + blockIdx.y;
    const int t  = threadIdx.x;
    const int w  = t >> 6;
    const int l  = t & 63;
    const int lg = l >> 4;     // 0..3
    const int lq = l & 15;     // this lane's q column

    __shared__ __align__(16) char lds[32768];
    // [0,8192): Khi tile [64][64] bf16 (swizzled)
    // [8192,16384): Klo tile
    // [16384,24576): Vt tile [64 d][64 j]
    // [24576,32768): P per wave: [16 q][64 j] bf16

    // Q fragments (registers, loaded once): B-operand of St = K·Q^T
    const size_t qbase = ((size_t)(bh * NN) + i0 + w * 16 + lq) * DDIM + lg * 8;
    bf16x8 qh[2], qlo[2];
    qh[0]  = *(const bf16x8*)(Qhi + qbase);
    qh[1]  = *(const bf16x8*)(Qhi + qbase + 32);
    qlo[0] = *(const bf16x8*)(Qlo + qbase);
    qlo[1] = *(const bf16x8*)(Qlo + qbase + 32);

    f32x4 Oa[4];
#pragma unroll
    for (int m = 0; m < 4; ++m) { Oa[m][0]=0.f; Oa[m][1]=0.f; Oa[m][2]=0.f; Oa[m][3]=0.f; }
    float m_run = -INFINITY, l_run = 0.f;

    char* Pw = lds + 24576 + w * 2048;

    for (int j0 = 0; j0 < NN; j0 += 64) {
        // ---- stage K hi/lo + Vt tiles (reg-staged, swizzled ds_write) ----
        uint4 gv[6];
#pragma unroll
        for (int i = 0; i < 6; ++i) {
            const int tile = i >> 1;               // 0 Khi, 1 Klo, 2 Vt
            const int idx  = ((i & 1) << 8) + t;   // 0..511
            const int row  = idx >> 3, cc = idx & 7;
            const bf16* src;
            if (tile == 0)      src = Khi + ((size_t)(bh * NN + j0 + row)) * DDIM + cc * 8;
            else if (tile == 1) src = Klo + ((size_t)(bh * NN + j0 + row)) * DDIM + cc * 8;
            else                src = Vt + ((size_t)(bh * DDIM + row) << 10) + j0 + cc * 8;
            gv[i] = *(const uint4*)src;
        }
        __syncthreads();   // all waves done reading previous tiles
#pragma unroll
        for (int i = 0; i < 6; ++i) {
            const int tile = i >> 1;
            const int idx  = ((i & 1) << 8) + t;
            const int row  = idx >> 3, cc = idx & 7;
            *(uint4*)(lds + tile * 8192 + row * 128 + ((cc ^ (row & 7)) << 4)) = gv[i];
        }
        __syncthreads();

        // ---- St = K·Q^T (rows j, cols q); split 3-term ----
        f32x4 S[4];
#pragma unroll
        for (int m = 0; m < 4; ++m) {
            f32x4 acc = {0.f, 0.f, 0.f, 0.f};
#pragma unroll
            for (int ks = 0; ks < 2; ++ks) {
                const int row = lq + 16 * m;
                const int ch  = ((lg + 4 * ks) ^ (row & 7)) << 4;
                bf16x8 kh = *(const bf16x8*)(lds + row * 128 + ch);
                bf16x8 kl = *(const bf16x8*)(lds + 8192 + row * 128 + ch);
                acc = MFMA16(kh, qh[ks], acc);
                acc = MFMA16(kh, qlo[ks], acc);
                acc = MFMA16(kl, qh[ks], acc);
            }
            S[m] = acc;
        }

        // ---- online softmax: lane holds 16 j's for q = lq ----
        float tm = S[0][0];
#pragma unroll
        for (int m = 0; m < 4; ++m)
#pragma unroll
            for (int r = 0; r < 4; ++r) tm = fmaxf(tm, S[m][r]);
        tm = fmaxf(tm, __shfl_xor(tm, 16));
        tm = fmaxf(tm, __shfl_xor(tm, 32));
        const float mnew = fmaxf(m_run, tm);
        const float corr = __expf(m_run - mnew);
        float ps[4][4];
        float psum = 0.f;
#pragma unroll
        for (int m = 0; m < 4; ++m)
#pragma unroll
            for (int r = 0; r < 4; ++r) {
                const float p = __expf(S[m][r] - mnew);
                ps[m][r] = p;
                psum += p;
            }
        psum += __shfl_xor(psum, 16);
        psum += __shfl_xor(psum, 32);
        l_run = l_run * corr + psum;
        m_run = mnew;
#pragma unroll
        for (int m = 0; m < 4; ++m)
#pragma unroll
            for (int r = 0; r < 4; ++r) Oa[m][r] *= corr;

        // ---- P -> per-wave LDS (bf16), j = 16f + 4*lg + r ----
#pragma unroll
        for (int f = 0; f < 4; ++f) {
            union { bf16 h[4]; uint2 u; } pu;
            pu.h[0] = (bf16)ps[f][0];
            pu.h[1] = (bf16)ps[f][1];
            pu.h[2] = (bf16)ps[f][2];
            pu.h[3] = (bf16)ps[f][3];
            *(uint2*)(Pw + lq * 128 + (((2 * f + (lg >> 1)) ^ (lq & 7)) << 4) + ((lg & 1) << 3)) = pu.u;
        }

        // ---- Ot += Vt · Pt ----
#pragma unroll
        for (int ks = 0; ks < 2; ++ks) {
            bf16x8 pb = *(const bf16x8*)(Pw + lq * 128 + (((lg + 4 * ks) ^ (lq & 7)) << 4));
#pragma unroll
            for (int m = 0; m < 4; ++m) {
                const int row = lq + 16 * m;
                bf16x8 va = *(const bf16x8*)(lds + 16384 + row * 128 + (((lg + 4 * ks) ^ (row & 7)) << 4));
                Oa[m] = MFMA16(va, pb, Oa[m]);
            }
        }
    }

    // ---- epilogue: O[b][h*64+d][i] = Oa/l ----
    const float inv = 1.0f / l_run;
#pragma unroll
    for (int m = 0; m < 4; ++m)
#pragma unroll
        for (int r = 0; r < 4; ++r) {
            const int d = 16 * m + 4 * lg + r;
            O[((size_t)(bh * DDIM + d) << 10) + i0 + w * 16 + lq] = Oa[m][r] * inv;
        }
}

// ---------------------------------------------------------------------------
// out[b,o,i] = sum_c Wout[o,c] * Obuf[b,c,i]   (Obuf channel-major from attn)
// ---------------------------------------------------------------------------
__global__ __launch_bounds__(256)
void outproj_kernel(const float* __restrict__ Obuf, const float* __restrict__ W,
                    float* __restrict__ out)
{
    const int i0 = blockIdx.x * 64;
    const int o0 = blockIdx.y * 64;
    const int b  = blockIdx.z;
    const int t  = threadIdx.x;
    const int tx = t & 15, ty = t >> 4;

    __shared__ float Ws[16][68];
    __shared__ float Xs[16][68];

    float acc[4][4] = {};          // [o_sub][i_sub]

    const int wo = t >> 2, wk = (t & 3) << 2;
    const int xk = t >> 4, xi = (t & 15) << 2;

    for (int k0 = 0; k0 < HID; k0 += 16) {
        const f4 w4 = *(const f4*)&W[(size_t)(o0 + wo) * HID + (k0 + wk)];
        const f4 x4 = *(const f4*)&Obuf[((size_t)(b * HID + k0 + xk) << 10) + i0 + xi];
        Ws[wk + 0][wo] = w4.x;
        Ws[wk + 1][wo] = w4.y;
        Ws[wk + 2][wo] = w4.z;
        Ws[wk + 3][wo] = w4.w;
        *(f4*)&Xs[xk][xi] = x4;
        __syncthreads();
#pragma unroll
        for (int kk = 0; kk < 16; ++kk) {
            float a[4], xv[4];
            *(f4*)a  = *(const f4*)&Ws[kk][ty << 2];   // o
            *(f4*)xv = *(const f4*)&Xs[kk][tx << 2];   // i
            fma4x4(acc, a, xv);
        }
        __syncthreads();
    }

#pragma unroll
    for (int r = 0; r < 4; ++r) {
        f4 v;
        v.x = acc[r][0]; v.y = acc[r][1]; v.z = acc[r][2]; v.w = acc[r][3];
        *(f4*)&out[((size_t)b * COUT + o0 + (ty << 2) + r) * NN + i0 + (tx << 2)] = v;
    }
}

// ---------------------------------------------------------------------------
extern "C" void kernel_launch(void* const* d_in, const int* in_sizes, int n_in,
                              void* d_out, int out_size, void* d_ws, size_t ws_size,
                              hipStream_t stream)
{
    const float* x_q   = (const float*)d_in[0];
    const float* x_kv  = (const float*)d_in[1];
    const float* w_q   = (const float*)d_in[2];
    const float* w_kv  = (const float*)d_in[3];
    const float* w_out = (const float*)d_in[4];
    float* out = (float*)d_out;

    char* ws = (char*)d_ws;
    const size_t nel = (size_t)BB * HID * NN;          // 4,194,304
    bf16* Qhi = (bf16*)(ws);
    bf16* Qlo = (bf16*)(ws + 2 * nel);
    bf16* Khi = (bf16*)(ws + 4 * nel);
    bf16* Klo = (bf16*)(ws + 6 * nel);
    bf16* Vt  = (bf16*)(ws + 8 * nel);
    float* O  = (float*)(ws + 10 * nel);               // f32, 16.8 MB

    dim3 blk(256);
    proj_split_kernel<320><<<dim3(16, 8, 8), blk, 0, stream>>>(x_q,  w_q,  Qhi, Qlo, 0.125f);
    proj_split_kernel<640><<<dim3(16, 8, 8), blk, 0, stream>>>(x_kv, w_kv, Khi, Klo, 1.0f);
    proj_vt_kernel<640><<<dim3(16, 8, 8), blk, 0, stream>>>(x_kv, w_kv + (size_t)HID * 640, Vt);
    attn_kernel<<<dim3(16, 8, 8), blk, 0, stream>>>(Qhi, Qlo, Khi, Klo, Vt, O);
    outproj_kernel<<<dim3(16, 5, 8), blk, 0, stream>>>(O, w_out, out);
}

// Round 3
// 309.090 us; speedup vs baseline: 1.6466x; 1.1641x over previous
//
#include <hip/hip_runtime.h>
#include <math.h>

#define BB   8
#define HH   8
#define DDIM 64
#define NN   1024
#define HID  512
#define COUT 320

typedef float4 f4;
typedef __bf16 bf16;
typedef __attribute__((ext_vector_type(8))) __bf16 bf16x8;
typedef __attribute__((ext_vector_type(4))) __bf16 bf16x4;
typedef __attribute__((ext_vector_type(4))) float f32x4;

#define MFMA16(a,b,c) __builtin_amdgcn_mfma_f32_16x16x32_bf16((a),(b),(c),0,0,0)

// ---------------------------------------------------------------------------
// Weight split-convert: W f32 [rows][CIN] -> Whi/Wlo bf16 (rows >= rows_valid
// are zero-filled, used to pad w_out to 384 rows). Grid sized exactly.
// ---------------------------------------------------------------------------
template<int CIN>
__global__ __launch_bounds__(256)
void conv_w_kernel(const float* __restrict__ W, bf16* __restrict__ Wh,
                   bf16* __restrict__ Wl, int rows_valid)
{
    const int idx = blockIdx.x * 256 + threadIdx.x;
    const int row = idx / (CIN / 4);
    const int c4  = (idx % (CIN / 4)) * 4;
    f4 v = {0.f, 0.f, 0.f, 0.f};
    if (row < rows_valid) v = *(const f4*)&W[(size_t)row * CIN + c4];
    const float vv[4] = {v.x, v.y, v.z, v.w};
    bf16x4 hv, lv;
#pragma unroll
    for (int e = 0; e < 4; ++e) {
        bf16 hb = (bf16)vv[e];
        hv[e] = hb;
        lv[e] = (bf16)(vv[e] - (float)hb);
    }
    *(bf16x4*)&Wh[(size_t)row * CIN + c4] = hv;
    *(bf16x4*)&Wl[(size_t)row * CIN + c4] = lv;
}

// ---------------------------------------------------------------------------
// Activation transpose-convert: X f32 [b][CIN][1024] -> Xt bf16 [b][1024][CIN]
// ---------------------------------------------------------------------------
template<int CIN>
__global__ __launch_bounds__(256)
void conv_xt_kernel(const float* __restrict__ X, bf16* __restrict__ Xt)
{
    __shared__ float Xs[64][68];
    const int n0 = blockIdx.x * 64;
    const int c0 = blockIdx.y * 64;
    const int b  = blockIdx.z;
    const int t  = threadIdx.x;
    const float* Xb = X + (size_t)b * CIN * NN;
#pragma unroll
    for (int it = 0; it < 4; ++it) {
        const int r  = it * 16 + (t >> 4);
        const int cc = (t & 15) * 4;
        *(f4*)&Xs[r][cc] = *(const f4*)&Xb[(size_t)(c0 + r) * NN + n0 + cc];
    }
    __syncthreads();
    const int n  = t >> 2;
    const int cb = (t & 3) * 16;
    union { bf16 h[16]; uint4 u[2]; } o;
#pragma unroll
    for (int e = 0; e < 16; ++e) o.h[e] = (bf16)Xs[cb + e][n];
    bf16* dst = Xt + ((size_t)b * NN + n0 + n) * CIN + c0 + cb;
    *(uint4*)dst = o.u[0];
    *(uint4*)(dst + 8) = o.u[1];
}

// ---------------------------------------------------------------------------
// Generic 2-term split-bf16 MFMA GEMM, 128x128 tile, BK=32, 4 waves (2x2).
// Both operands [free][K]-major bf16. One operand has hi/lo split (ASPLIT).
// C rows = A-free, cols = B-free. LDS chunk-XOR swizzle: chunkpos = cg ^ ((row>>1)&3).
// EPI 0/1: A=W(o) B=Xt(i): split-bf16 stores to D0/D1 [bh][n][64], *scale
// EPI 2:   A=Xt(i) B=Wv(o): bf16 stores to D0 = Vt [bh][64][1024]
// EPI 3:   A=Ot(i) B=Wout(o): f32 f4 stores to Df = out [b][320][1024], o<320
// ---------------------------------------------------------------------------
#define SLOT_A  0
#define SLOT_AL 8192
#define SLOT_B  16384
#define SLOT_BL 24576

template<int K, int ASPLIT, int EPI>
__global__ __launch_bounds__(256)
void gemm2t_kernel(const bf16* __restrict__ Ah, const bf16* __restrict__ Al,
                   const bf16* __restrict__ Bh, const bf16* __restrict__ Bl,
                   long a_bstride, long b_bstride,
                   bf16* __restrict__ D0, bf16* __restrict__ D1,
                   float* __restrict__ Df, float scale)
{
    __shared__ __align__(16) char lds[32768];
    const int t  = threadIdx.x;
    const int w  = t >> 6, l = t & 63;
    const int lg = l >> 4, lq = l & 15;
    const int wa = w >> 1, wb = w & 1;
    const int b  = blockIdx.z;
    const int arow0 = blockIdx.y * 128;
    const int brow0 = blockIdx.x * 128;

    const bf16* Ab  = Ah + (size_t)b * a_bstride;
    const bf16* Alb = ASPLIT ? (Al + (size_t)b * a_bstride) : (const bf16*)nullptr;
    const bf16* Bb  = Bh + (size_t)b * b_bstride;
    const bf16* Blb = ASPLIT ? (const bf16*)nullptr : (Bl + (size_t)b * b_bstride);

    const int srow = t >> 2;                         // staging row (j=0 half)
    const int scg  = (t & 3) ^ ((t >> 3) & 3);       // swizzled global chunk
    const int wbyte = srow * 64 + (t & 3) * 16;      // staging LDS byte offset

    f32x4 acc[4][4];
#pragma unroll
    for (int i = 0; i < 4; ++i)
#pragma unroll
        for (int j = 0; j < 4; ++j) acc[i][j] = (f32x4){0.f, 0.f, 0.f, 0.f};

    constexpr int NK = K / 32;
    uint4 gv[6];

    // prologue load (k-step 0)
#pragma unroll
    for (int j = 0; j < 2; ++j) {
        const int row = j * 64 + srow;
        const size_t koff = scg * 8;
        gv[j]     = *(const uint4*)(Ab + (size_t)(arow0 + row) * K + koff);
        gv[4 + j] = *(const uint4*)(Bb + (size_t)(brow0 + row) * K + koff);
        gv[2 + j] = ASPLIT ? *(const uint4*)(Alb + (size_t)(arow0 + row) * K + koff)
                           : *(const uint4*)(Blb + (size_t)(brow0 + row) * K + koff);
    }

    for (int ks = 0; ks < NK; ++ks) {
        // write staged regs into LDS
#pragma unroll
        for (int j = 0; j < 2; ++j) {
            const int off = j * 4096 + wbyte;
            *(uint4*)(lds + SLOT_A + off) = gv[j];
            *(uint4*)(lds + SLOT_B + off) = gv[4 + j];
            *(uint4*)(lds + (ASPLIT ? SLOT_AL : SLOT_BL) + off) = gv[2 + j];
        }
        __syncthreads();

        // issue next-step global loads early (hide under MFMA)
        if (ks + 1 < NK) {
            const size_t k0 = (size_t)(ks + 1) * 32 + scg * 8;
#pragma unroll
            for (int j = 0; j < 2; ++j) {
                const int row = j * 64 + srow;
                gv[j]     = *(const uint4*)(Ab + (size_t)(arow0 + row) * K + k0);
                gv[4 + j] = *(const uint4*)(Bb + (size_t)(brow0 + row) * K + k0);
                gv[2 + j] = ASPLIT ? *(const uint4*)(Alb + (size_t)(arow0 + row) * K + k0)
                                   : *(const uint4*)(Blb + (size_t)(brow0 + row) * K + k0);
            }
        }

        // compute on current LDS tile
        bf16x8 a0[4], a1[4], b0[4], b1[4];
#pragma unroll
        for (int m = 0; m < 4; ++m) {
            const int rA = wa * 64 + 16 * m + lq;
            const int offA = rA * 64 + ((lg ^ ((rA >> 1) & 3)) << 4);
            a0[m] = *(const bf16x8*)(lds + SLOT_A + offA);
            if (ASPLIT) a1[m] = *(const bf16x8*)(lds + SLOT_AL + offA);
            const int rB = wb * 64 + 16 * m + lq;
            const int offB = rB * 64 + ((lg ^ ((rB >> 1) & 3)) << 4);
            b0[m] = *(const bf16x8*)(lds + SLOT_B + offB);
            if (!ASPLIT) b1[m] = *(const bf16x8*)(lds + SLOT_BL + offB);
        }
#pragma unroll
        for (int mA = 0; mA < 4; ++mA)
#pragma unroll
            for (int mB = 0; mB < 4; ++mB) {
                acc[mA][mB] = MFMA16(a0[mA], b0[mB], acc[mA][mB]);
                acc[mA][mB] = ASPLIT ? MFMA16(a1[mA], b0[mB], acc[mA][mB])
                                     : MFMA16(a0[mA], b1[mB], acc[mA][mB]);
            }
        __syncthreads();
    }

    // epilogue
#pragma unroll
    for (int mA = 0; mA < 4; ++mA)
#pragma unroll
        for (int mB = 0; mB < 4; ++mB) {
            if (EPI <= 1) {          // Q/K: split stores to [bh][n][64]
                const int o = arow0 + wa * 64 + 16 * mA + 4 * lg;
                const int i = brow0 + wb * 64 + 16 * mB + lq;
                const int h = o >> 6, d = o & 63;
                const size_t base = ((size_t)((b * HH + h) * NN + i)) * 64 + d;
                bf16x4 hv, lv;
#pragma unroll
                for (int r = 0; r < 4; ++r) {
                    const float v = acc[mA][mB][r] * scale;
                    bf16 hb = (bf16)v;
                    hv[r] = hb;
                    lv[r] = (bf16)(v - (float)hb);
                }
                *(bf16x4*)(D0 + base) = hv;
                *(bf16x4*)(D1 + base) = lv;
            } else if (EPI == 2) {   // V: bf16 stores to Vt [bh][64][1024]
                const int i = arow0 + wa * 64 + 16 * mA + 4 * lg;
                const int o = brow0 + wb * 64 + 16 * mB + lq;
                const int h = o >> 6, d = o & 63;
                const size_t base = ((size_t)((b * HH + h) * DDIM + d)) * NN + i;
                bf16x4 pv;
#pragma unroll
                for (int r = 0; r < 4; ++r) pv[r] = (bf16)acc[mA][mB][r];
                *(bf16x4*)(D0 + base) = pv;
            } else {                 // out: f32 stores to [b][320][1024]
                const int i = arow0 + wa * 64 + 16 * mA + 4 * lg;
                const int o = brow0 + wb * 64 + 16 * mB + lq;
                if (o < COUT)
                    *(f32x4*)(Df + ((size_t)(b * COUT + o)) * NN + i) = acc[mA][mB];
            }
        }
}

// ---------------------------------------------------------------------------
// MFMA flash attention (unchanged core from round 2; epilogue now writes
// Ot bf16 [b][n][512] K-major for the out-projection).
// ---------------------------------------------------------------------------
__global__ __launch_bounds__(256)
void attn_kernel(const bf16* __restrict__ Qhi, const bf16* __restrict__ Qlo,
                 const bf16* __restrict__ Khi, const bf16* __restrict__ Klo,
                 const bf16* __restrict__ Vt,  bf16* __restrict__ Ot)
{
    const int i0 = blockIdx.x * 64;
    const int bh = blockIdx.z * HH + blockIdx.y;
    const int t  = threadIdx.x;
    const int w  = t >> 6;
    const int l  = t & 63;
    const int lg = l >> 4;
    const int lq = l & 15;

    __shared__ __align__(16) char lds[32768];

    const size_t qbase = ((size_t)(bh * NN) + i0 + w * 16 + lq) * DDIM + lg * 8;
    bf16x8 qh[2], qlo[2];
    qh[0]  = *(const bf16x8*)(Qhi + qbase);
    qh[1]  = *(const bf16x8*)(Qhi + qbase + 32);
    qlo[0] = *(const bf16x8*)(Qlo + qbase);
    qlo[1] = *(const bf16x8*)(Qlo + qbase + 32);

    f32x4 Oa[4];
#pragma unroll
    for (int m = 0; m < 4; ++m) { Oa[m][0]=0.f; Oa[m][1]=0.f; Oa[m][2]=0.f; Oa[m][3]=0.f; }
    float m_run = -INFINITY, l_run = 0.f;

    char* Pw = lds + 24576 + w * 2048;

    for (int j0 = 0; j0 < NN; j0 += 64) {
        uint4 gv[6];
#pragma unroll
        for (int i = 0; i < 6; ++i) {
            const int tile = i >> 1;
            const int idx  = ((i & 1) << 8) + t;
            const int row  = idx >> 3, cc = idx & 7;
            const bf16* src;
            if (tile == 0)      src = Khi + ((size_t)(bh * NN + j0 + row)) * DDIM + cc * 8;
            else if (tile == 1) src = Klo + ((size_t)(bh * NN + j0 + row)) * DDIM + cc * 8;
            else                src = Vt + ((size_t)(bh * DDIM + row) << 10) + j0 + cc * 8;
            gv[i] = *(const uint4*)src;
        }
        __syncthreads();
#pragma unroll
        for (int i = 0; i < 6; ++i) {
            const int tile = i >> 1;
            const int idx  = ((i & 1) << 8) + t;
            const int row  = idx >> 3, cc = idx & 7;
            *(uint4*)(lds + tile * 8192 + row * 128 + ((cc ^ (row & 7)) << 4)) = gv[i];
        }
        __syncthreads();

        f32x4 S[4];
#pragma unroll
        for (int m = 0; m < 4; ++m) {
            f32x4 acc = {0.f, 0.f, 0.f, 0.f};
#pragma unroll
            for (int ks = 0; ks < 2; ++ks) {
                const int row = lq + 16 * m;
                const int ch  = ((lg + 4 * ks) ^ (row & 7)) << 4;
                bf16x8 kh = *(const bf16x8*)(lds + row * 128 + ch);
                bf16x8 kl = *(const bf16x8*)(lds + 8192 + row * 128 + ch);
                acc = MFMA16(kh, qh[ks], acc);
                acc = MFMA16(kh, qlo[ks], acc);
                acc = MFMA16(kl, qh[ks], acc);
            }
            S[m] = acc;
        }

        float tm = S[0][0];
#pragma unroll
        for (int m = 0; m < 4; ++m)
#pragma unroll
            for (int r = 0; r < 4; ++r) tm = fmaxf(tm, S[m][r]);
        tm = fmaxf(tm, __shfl_xor(tm, 16));
        tm = fmaxf(tm, __shfl_xor(tm, 32));
        const float mnew = fmaxf(m_run, tm);
        const float corr = __expf(m_run - mnew);
        float ps[4][4];
        float psum = 0.f;
#pragma unroll
        for (int m = 0; m < 4; ++m)
#pragma unroll
            for (int r = 0; r < 4; ++r) {
                const float p = __expf(S[m][r] - mnew);
                ps[m][r] = p;
                psum += p;
            }
        psum += __shfl_xor(psum, 16);
        psum += __shfl_xor(psum, 32);
        l_run = l_run * corr + psum;
        m_run = mnew;
#pragma unroll
        for (int m = 0; m < 4; ++m)
#pragma unroll
            for (int r = 0; r < 4; ++r) Oa[m][r] *= corr;

#pragma unroll
        for (int f = 0; f < 4; ++f) {
            union { bf16 h[4]; uint2 u; } pu;
            pu.h[0] = (bf16)ps[f][0];
            pu.h[1] = (bf16)ps[f][1];
            pu.h[2] = (bf16)ps[f][2];
            pu.h[3] = (bf16)ps[f][3];
            *(uint2*)(Pw + lq * 128 + (((2 * f + (lg >> 1)) ^ (lq & 7)) << 4) + ((lg & 1) << 3)) = pu.u;
        }

#pragma unroll
        for (int ks = 0; ks < 2; ++ks) {
            bf16x8 pb = *(const bf16x8*)(Pw + lq * 128 + (((lg + 4 * ks) ^ (lq & 7)) << 4));
#pragma unroll
            for (int m = 0; m < 4; ++m) {
                const int row = lq + 16 * m;
                bf16x8 va = *(const bf16x8*)(lds + 16384 + row * 128 + (((lg + 4 * ks) ^ (row & 7)) << 4));
                Oa[m] = MFMA16(va, pb, Oa[m]);
            }
        }
    }

    // epilogue: Ot[b][i][h*64+d] bf16
    const float inv = 1.0f / l_run;
    const int i = i0 + w * 16 + lq;
    const size_t obase = ((size_t)(blockIdx.z * NN) + i) * HID + blockIdx.y * DDIM;
#pragma unroll
    for (int m = 0; m < 4; ++m) {
        bf16x4 ov;
#pragma unroll
        for (int r = 0; r < 4; ++r) ov[r] = (bf16)(Oa[m][r] * inv);
        *(bf16x4*)(Ot + obase + 16 * m + 4 * lg) = ov;
    }
}

// ---------------------------------------------------------------------------
extern "C" void kernel_launch(void* const* d_in, const int* in_sizes, int n_in,
                              void* d_out, int out_size, void* d_ws, size_t ws_size,
                              hipStream_t stream)
{
    const float* x_q   = (const float*)d_in[0];
    const float* x_kv  = (const float*)d_in[1];
    const float* w_q   = (const float*)d_in[2];
    const float* w_kv  = (const float*)d_in[3];
    const float* w_out = (const float*)d_in[4];
    float* out = (float*)d_out;

    char* ws = (char*)d_ws;
    // workspace layout (bytes); Ot aliases the dead Xtq/Xtkv region
    bf16* Xtq   = (bf16*)(ws + 0);          //  5,242,880
    bf16* Ot    = (bf16*)(ws + 0);          //  8,388,608 (after projections done)
    bf16* Xtkv  = (bf16*)(ws + 5242880);    // 10,485,760
    bf16* Wqh   = (bf16*)(ws + 15728640);   //    327,680
    bf16* Wql   = (bf16*)(ws + 16056320);   //    327,680
    bf16* Wkvh  = (bf16*)(ws + 16384000);   //  1,310,720
    bf16* Wkvl  = (bf16*)(ws + 17694720);   //  1,310,720
    bf16* Wouth = (bf16*)(ws + 19005440);   //    393,216
    bf16* Woutl = (bf16*)(ws + 19398656);   //    393,216
    bf16* Qhi   = (bf16*)(ws + 19791872);   //  8,388,608
    bf16* Qlo   = (bf16*)(ws + 28180480);   //  8,388,608
    bf16* Khi   = (bf16*)(ws + 36569088);   //  8,388,608
    bf16* Klo   = (bf16*)(ws + 44957696);   //  8,388,608
    bf16* Vt    = (bf16*)(ws + 53346304);   //  8,388,608  -> end 61,734,912

    dim3 blk(256);
    conv_xt_kernel<320><<<dim3(16, 5, 8),  blk, 0, stream>>>(x_q,  Xtq);
    conv_xt_kernel<640><<<dim3(16, 10, 8), blk, 0, stream>>>(x_kv, Xtkv);
    conv_w_kernel<320><<<160, blk, 0, stream>>>(w_q,   Wqh,   Wql,   512);
    conv_w_kernel<640><<<640, blk, 0, stream>>>(w_kv,  Wkvh,  Wkvl,  1024);
    conv_w_kernel<512><<<192, blk, 0, stream>>>(w_out, Wouth, Woutl, 320);

    gemm2t_kernel<320, 1, 0><<<dim3(8, 4, 8), blk, 0, stream>>>(
        Wqh, Wql, Xtq, nullptr, 0, (long)NN * 320, Qhi, Qlo, nullptr, 0.125f);
    gemm2t_kernel<640, 1, 0><<<dim3(8, 4, 8), blk, 0, stream>>>(
        Wkvh, Wkvl, Xtkv, nullptr, 0, (long)NN * 640, Khi, Klo, nullptr, 1.0f);
    gemm2t_kernel<640, 0, 2><<<dim3(4, 8, 8), blk, 0, stream>>>(
        Xtkv, nullptr, Wkvh + (size_t)HID * 640, Wkvl + (size_t)HID * 640,
        (long)NN * 640, 0, Vt, nullptr, nullptr, 1.0f);

    attn_kernel<<<dim3(16, 8, 8), blk, 0, stream>>>(Qhi, Qlo, Khi, Klo, Vt, Ot);

    gemm2t_kernel<512, 0, 3><<<dim3(3, 8, 8), blk, 0, stream>>>(
        Ot, nullptr, Wouth, Woutl, (long)NN * HID, 0, nullptr, nullptr, out, 1.0f);
}

// Round 4
// 288.481 us; speedup vs baseline: 1.7643x; 1.0714x over previous
//
#include <hip/hip_runtime.h>
#include <math.h>

#define BB   8
#define HH   8
#define DDIM 64
#define NN   1024
#define HID  512
#define COUT 320

typedef float4 f4;
typedef __bf16 bf16;
typedef __attribute__((ext_vector_type(8))) __bf16 bf16x8;
typedef __attribute__((ext_vector_type(4))) __bf16 bf16x4;
typedef __attribute__((ext_vector_type(4))) float f32x4;

#define MFMA16(a,b,c) __builtin_amdgcn_mfma_f32_16x16x32_bf16((a),(b),(c),0,0,0)

// ---------------------------------------------------------------------------
// Weight split-convert: W f32 [rows][CIN] -> Whi/Wlo bf16 (rows >= rows_valid
// are zero-filled, used to pad w_out to 384 rows). Grid sized exactly.
// ---------------------------------------------------------------------------
template<int CIN>
__global__ __launch_bounds__(256)
void conv_w_kernel(const float* __restrict__ W, bf16* __restrict__ Wh,
                   bf16* __restrict__ Wl, int rows_valid)
{
    const int idx = blockIdx.x * 256 + threadIdx.x;
    const int row = idx / (CIN / 4);
    const int c4  = (idx % (CIN / 4)) * 4;
    f4 v = {0.f, 0.f, 0.f, 0.f};
    if (row < rows_valid) v = *(const f4*)&W[(size_t)row * CIN + c4];
    const float vv[4] = {v.x, v.y, v.z, v.w};
    bf16x4 hv, lv;
#pragma unroll
    for (int e = 0; e < 4; ++e) {
        bf16 hb = (bf16)vv[e];
        hv[e] = hb;
        lv[e] = (bf16)(vv[e] - (float)hb);
    }
    *(bf16x4*)&Wh[(size_t)row * CIN + c4] = hv;
    *(bf16x4*)&Wl[(size_t)row * CIN + c4] = lv;
}

// ---------------------------------------------------------------------------
// Activation transpose-convert: X f32 [b][CIN][1024] -> Xt bf16 [b][1024][CIN]
// ---------------------------------------------------------------------------
template<int CIN>
__global__ __launch_bounds__(256)
void conv_xt_kernel(const float* __restrict__ X, bf16* __restrict__ Xt)
{
    __shared__ float Xs[64][68];
    const int n0 = blockIdx.x * 64;
    const int c0 = blockIdx.y * 64;
    const int b  = blockIdx.z;
    const int t  = threadIdx.x;
    const float* Xb = X + (size_t)b * CIN * NN;
#pragma unroll
    for (int it = 0; it < 4; ++it) {
        const int r  = it * 16 + (t >> 4);
        const int cc = (t & 15) * 4;
        *(f4*)&Xs[r][cc] = *(const f4*)&Xb[(size_t)(c0 + r) * NN + n0 + cc];
    }
    __syncthreads();
    const int n  = t >> 2;
    const int cb = (t & 3) * 16;
    union { bf16 h[16]; uint4 u[2]; } o;
#pragma unroll
    for (int e = 0; e < 16; ++e) o.h[e] = (bf16)Xs[cb + e][n];
    bf16* dst = Xt + ((size_t)b * NN + n0 + n) * CIN + c0 + cb;
    *(uint4*)dst = o.u[0];
    *(uint4*)(dst + 8) = o.u[1];
}

// ---------------------------------------------------------------------------
// Generic 2-term split-bf16 MFMA GEMM, 128x128 tile, BK=32, 4 waves (2x2).
// ---------------------------------------------------------------------------
#define SLOT_A  0
#define SLOT_AL 8192
#define SLOT_B  16384
#define SLOT_BL 24576

template<int K, int ASPLIT, int EPI>
__global__ __launch_bounds__(256)
void gemm2t_kernel(const bf16* __restrict__ Ah, const bf16* __restrict__ Al,
                   const bf16* __restrict__ Bh, const bf16* __restrict__ Bl,
                   long a_bstride, long b_bstride,
                   bf16* __restrict__ D0, bf16* __restrict__ D1,
                   float* __restrict__ Df, float scale)
{
    __shared__ __align__(16) char lds[32768];
    const int t  = threadIdx.x;
    const int w  = t >> 6, l = t & 63;
    const int lg = l >> 4, lq = l & 15;
    const int wa = w >> 1, wb = w & 1;
    const int b  = blockIdx.z;
    const int arow0 = blockIdx.y * 128;
    const int brow0 = blockIdx.x * 128;

    const bf16* Ab  = Ah + (size_t)b * a_bstride;
    const bf16* Alb = ASPLIT ? (Al + (size_t)b * a_bstride) : (const bf16*)nullptr;
    const bf16* Bb  = Bh + (size_t)b * b_bstride;
    const bf16* Blb = ASPLIT ? (const bf16*)nullptr : (Bl + (size_t)b * b_bstride);

    const int srow = t >> 2;
    const int scg  = (t & 3) ^ ((t >> 3) & 3);
    const int wbyte = srow * 64 + (t & 3) * 16;

    f32x4 acc[4][4];
#pragma unroll
    for (int i = 0; i < 4; ++i)
#pragma unroll
        for (int j = 0; j < 4; ++j) acc[i][j] = (f32x4){0.f, 0.f, 0.f, 0.f};

    constexpr int NK = K / 32;
    uint4 gv[6];

#pragma unroll
    for (int j = 0; j < 2; ++j) {
        const int row = j * 64 + srow;
        const size_t koff = scg * 8;
        gv[j]     = *(const uint4*)(Ab + (size_t)(arow0 + row) * K + koff);
        gv[4 + j] = *(const uint4*)(Bb + (size_t)(brow0 + row) * K + koff);
        gv[2 + j] = ASPLIT ? *(const uint4*)(Alb + (size_t)(arow0 + row) * K + koff)
                           : *(const uint4*)(Blb + (size_t)(brow0 + row) * K + koff);
    }

    for (int ks = 0; ks < NK; ++ks) {
#pragma unroll
        for (int j = 0; j < 2; ++j) {
            const int off = j * 4096 + wbyte;
            *(uint4*)(lds + SLOT_A + off) = gv[j];
            *(uint4*)(lds + SLOT_B + off) = gv[4 + j];
            *(uint4*)(lds + (ASPLIT ? SLOT_AL : SLOT_BL) + off) = gv[2 + j];
        }
        __syncthreads();

        if (ks + 1 < NK) {
            const size_t k0 = (size_t)(ks + 1) * 32 + scg * 8;
#pragma unroll
            for (int j = 0; j < 2; ++j) {
                const int row = j * 64 + srow;
                gv[j]     = *(const uint4*)(Ab + (size_t)(arow0 + row) * K + k0);
                gv[4 + j] = *(const uint4*)(Bb + (size_t)(brow0 + row) * K + k0);
                gv[2 + j] = ASPLIT ? *(const uint4*)(Alb + (size_t)(arow0 + row) * K + k0)
                                   : *(const uint4*)(Blb + (size_t)(brow0 + row) * K + k0);
            }
        }

        bf16x8 a0[4], a1[4], b0[4], b1[4];
#pragma unroll
        for (int m = 0; m < 4; ++m) {
            const int rA = wa * 64 + 16 * m + lq;
            const int offA = rA * 64 + ((lg ^ ((rA >> 1) & 3)) << 4);
            a0[m] = *(const bf16x8*)(lds + SLOT_A + offA);
            if (ASPLIT) a1[m] = *(const bf16x8*)(lds + SLOT_AL + offA);
            const int rB = wb * 64 + 16 * m + lq;
            const int offB = rB * 64 + ((lg ^ ((rB >> 1) & 3)) << 4);
            b0[m] = *(const bf16x8*)(lds + SLOT_B + offB);
            if (!ASPLIT) b1[m] = *(const bf16x8*)(lds + SLOT_BL + offB);
        }
        __builtin_amdgcn_s_setprio(1);
#pragma unroll
        for (int mA = 0; mA < 4; ++mA)
#pragma unroll
            for (int mB = 0; mB < 4; ++mB) {
                acc[mA][mB] = MFMA16(a0[mA], b0[mB], acc[mA][mB]);
                acc[mA][mB] = ASPLIT ? MFMA16(a1[mA], b0[mB], acc[mA][mB])
                                     : MFMA16(a0[mA], b1[mB], acc[mA][mB]);
            }
        __builtin_amdgcn_s_setprio(0);
        __syncthreads();
    }

#pragma unroll
    for (int mA = 0; mA < 4; ++mA)
#pragma unroll
        for (int mB = 0; mB < 4; ++mB) {
            if (EPI <= 1) {
                const int o = arow0 + wa * 64 + 16 * mA + 4 * lg;
                const int i = brow0 + wb * 64 + 16 * mB + lq;
                const int h = o >> 6, d = o & 63;
                const size_t base = ((size_t)((b * HH + h) * NN + i)) * 64 + d;
                bf16x4 hv, lv;
#pragma unroll
                for (int r = 0; r < 4; ++r) {
                    const float v = acc[mA][mB][r] * scale;
                    bf16 hb = (bf16)v;
                    hv[r] = hb;
                    lv[r] = (bf16)(v - (float)hb);
                }
                *(bf16x4*)(D0 + base) = hv;
                *(bf16x4*)(D1 + base) = lv;
            } else if (EPI == 2) {
                const int i = arow0 + wa * 64 + 16 * mA + 4 * lg;
                const int o = brow0 + wb * 64 + 16 * mB + lq;
                const int h = o >> 6, d = o & 63;
                const size_t base = ((size_t)((b * HH + h) * DDIM + d)) * NN + i;
                bf16x4 pv;
#pragma unroll
                for (int r = 0; r < 4; ++r) pv[r] = (bf16)acc[mA][mB][r];
                *(bf16x4*)(D0 + base) = pv;
            } else {
                const int i = arow0 + wa * 64 + 16 * mA + 4 * lg;
                const int o = brow0 + wb * 64 + 16 * mB + lq;
                if (o < COUT)
                    *(f32x4*)(Df + ((size_t)(b * COUT + o)) * NN + i) = acc[mA][mB];
            }
        }
}

// ---------------------------------------------------------------------------
// MFMA flash attention, round-4: XCD-chunk swizzled grid (all 16 i0-blocks of
// a bh land on one XCD -> K/V served from that XCD's L2), reg-prefetch staging
// (next tile's global loads issued before compute, latency hides under MFMA),
// setprio around MFMA clusters.
// grid: 1024 linear blocks, 256 threads.
// ---------------------------------------------------------------------------
__global__ __launch_bounds__(256)
void attn_kernel(const bf16* __restrict__ Qhi, const bf16* __restrict__ Qlo,
                 const bf16* __restrict__ Khi, const bf16* __restrict__ Klo,
                 const bf16* __restrict__ Vt,  bf16* __restrict__ Ot)
{
    const int id  = blockIdx.x;
    const int loc = id >> 3;
    const int bh  = (id & 7) * 8 + (loc >> 4);   // 8 bh per XCD
    const int i0  = (loc & 15) * 64;
    const int b   = bh >> 3, h = bh & 7;
    const int t   = threadIdx.x;
    const int w   = t >> 6;
    const int l   = t & 63;
    const int lg  = l >> 4;
    const int lq  = l & 15;

    __shared__ __align__(16) char lds[32768];
    // [0,8192) Khi [64][64] swz; [8192,16384) Klo; [16384,24576) Vt; [24576,32768) P

    // Q fragments (registers, loaded once)
    const size_t qbase = ((size_t)(bh * NN) + i0 + w * 16 + lq) * DDIM + lg * 8;
    bf16x8 qh[2], qlo[2];
    qh[0]  = *(const bf16x8*)(Qhi + qbase);
    qh[1]  = *(const bf16x8*)(Qhi + qbase + 32);
    qlo[0] = *(const bf16x8*)(Qlo + qbase);
    qlo[1] = *(const bf16x8*)(Qlo + qbase + 32);

    // staging pointers: each thread loads rows {srow, srow+32}, chunk scc
    const int srow = t >> 3;     // 0..31
    const int scc  = t & 7;
    const bf16* pKh = Khi + ((size_t)(bh * NN) + srow) * DDIM + scc * 8;
    const bf16* pKl = Klo + ((size_t)(bh * NN) + srow) * DDIM + scc * 8;
    const bf16* pV  = Vt  + (((size_t)(bh * DDIM) + srow) << 10) + scc * 8;
    const int dwA = srow * 128 + ((scc ^ (srow & 7)) << 4);   // +4096 for row+32

    uint4 gv[6];
    gv[0] = *(const uint4*)(pKh);
    gv[1] = *(const uint4*)(pKh + 32 * DDIM);
    gv[2] = *(const uint4*)(pKl);
    gv[3] = *(const uint4*)(pKl + 32 * DDIM);
    gv[4] = *(const uint4*)(pV);
    gv[5] = *(const uint4*)(pV + (32 << 10));

    f32x4 Oa[4];
#pragma unroll
    for (int m = 0; m < 4; ++m) { Oa[m][0]=0.f; Oa[m][1]=0.f; Oa[m][2]=0.f; Oa[m][3]=0.f; }
    float m_run = -INFINITY, l_run = 0.f;

    char* Pw = lds + 24576 + w * 2048;

    for (int jt = 0; jt < 16; ++jt) {
        __syncthreads();   // all waves done reading previous tiles
        *(uint4*)(lds +         dwA)        = gv[0];
        *(uint4*)(lds +         dwA + 4096) = gv[1];
        *(uint4*)(lds +  8192 + dwA)        = gv[2];
        *(uint4*)(lds +  8192 + dwA + 4096) = gv[3];
        *(uint4*)(lds + 16384 + dwA)        = gv[4];
        *(uint4*)(lds + 16384 + dwA + 4096) = gv[5];
        __syncthreads();

        // prefetch next tile (latency hides under compute below)
        if (jt + 1 < 16) {
            pKh += 64 * DDIM; pKl += 64 * DDIM; pV += 64;
            gv[0] = *(const uint4*)(pKh);
            gv[1] = *(const uint4*)(pKh + 32 * DDIM);
            gv[2] = *(const uint4*)(pKl);
            gv[3] = *(const uint4*)(pKl + 32 * DDIM);
            gv[4] = *(const uint4*)(pV);
            gv[5] = *(const uint4*)(pV + (32 << 10));
        }

        // ---- St = K·Q^T (rows j, cols q); split 3-term ----
        f32x4 S[4];
#pragma unroll
        for (int m = 0; m < 4; ++m) {
            f32x4 acc = {0.f, 0.f, 0.f, 0.f};
#pragma unroll
            for (int ks = 0; ks < 2; ++ks) {
                const int row = lq + 16 * m;
                const int ch  = ((lg + 4 * ks) ^ (row & 7)) << 4;
                bf16x8 kh = *(const bf16x8*)(lds + row * 128 + ch);
                bf16x8 kl = *(const bf16x8*)(lds + 8192 + row * 128 + ch);
                __builtin_amdgcn_s_setprio(1);
                acc = MFMA16(kh, qh[ks], acc);
                acc = MFMA16(kh, qlo[ks], acc);
                acc = MFMA16(kl, qh[ks], acc);
                __builtin_amdgcn_s_setprio(0);
            }
            S[m] = acc;
        }

        // ---- online softmax: lane holds 16 j's for q = lq ----
        float tm = S[0][0];
#pragma unroll
        for (int m = 0; m < 4; ++m)
#pragma unroll
            for (int r = 0; r < 4; ++r) tm = fmaxf(tm, S[m][r]);
        tm = fmaxf(tm, __shfl_xor(tm, 16));
        tm = fmaxf(tm, __shfl_xor(tm, 32));
        const float mnew = fmaxf(m_run, tm);
        const float corr = __expf(m_run - mnew);
        float ps[4][4];
        float psum = 0.f;
#pragma unroll
        for (int m = 0; m < 4; ++m)
#pragma unroll
            for (int r = 0; r < 4; ++r) {
                const float p = __expf(S[m][r] - mnew);
                ps[m][r] = p;
                psum += p;
            }
        psum += __shfl_xor(psum, 16);
        psum += __shfl_xor(psum, 32);
        l_run = l_run * corr + psum;
        m_run = mnew;
#pragma unroll
        for (int m = 0; m < 4; ++m)
#pragma unroll
            for (int r = 0; r < 4; ++r) Oa[m][r] *= corr;

        // ---- P -> per-wave LDS (bf16) ----
#pragma unroll
        for (int f = 0; f < 4; ++f) {
            union { bf16 hh[4]; uint2 u; } pu;
            pu.hh[0] = (bf16)ps[f][0];
            pu.hh[1] = (bf16)ps[f][1];
            pu.hh[2] = (bf16)ps[f][2];
            pu.hh[3] = (bf16)ps[f][3];
            *(uint2*)(Pw + lq * 128 + (((2 * f + (lg >> 1)) ^ (lq & 7)) << 4) + ((lg & 1) << 3)) = pu.u;
        }

        // ---- Ot += Vt · Pt ----
#pragma unroll
        for (int ks = 0; ks < 2; ++ks) {
            bf16x8 pb = *(const bf16x8*)(Pw + lq * 128 + (((lg + 4 * ks) ^ (lq & 7)) << 4));
            __builtin_amdgcn_s_setprio(1);
#pragma unroll
            for (int m = 0; m < 4; ++m) {
                const int row = lq + 16 * m;
                bf16x8 va = *(const bf16x8*)(lds + 16384 + row * 128 + (((lg + 4 * ks) ^ (row & 7)) << 4));
                Oa[m] = MFMA16(va, pb, Oa[m]);
            }
            __builtin_amdgcn_s_setprio(0);
        }
    }

    // epilogue: Ot[b][i][h*64+d] bf16
    const float inv = 1.0f / l_run;
    const int i = i0 + w * 16 + lq;
    const size_t obase = ((size_t)(b * NN) + i) * HID + h * DDIM;
#pragma unroll
    for (int m = 0; m < 4; ++m) {
        bf16x4 ov;
#pragma unroll
        for (int r = 0; r < 4; ++r) ov[r] = (bf16)(Oa[m][r] * inv);
        *(bf16x4*)(Ot + obase + 16 * m + 4 * lg) = ov;
    }
}

// ---------------------------------------------------------------------------
extern "C" void kernel_launch(void* const* d_in, const int* in_sizes, int n_in,
                              void* d_out, int out_size, void* d_ws, size_t ws_size,
                              hipStream_t stream)
{
    const float* x_q   = (const float*)d_in[0];
    const float* x_kv  = (const float*)d_in[1];
    const float* w_q   = (const float*)d_in[2];
    const float* w_kv  = (const float*)d_in[3];
    const float* w_out = (const float*)d_in[4];
    float* out = (float*)d_out;

    char* ws = (char*)d_ws;
    bf16* Xtq   = (bf16*)(ws + 0);
    bf16* Ot    = (bf16*)(ws + 0);
    bf16* Xtkv  = (bf16*)(ws + 5242880);
    bf16* Wqh   = (bf16*)(ws + 15728640);
    bf16* Wql   = (bf16*)(ws + 16056320);
    bf16* Wkvh  = (bf16*)(ws + 16384000);
    bf16* Wkvl  = (bf16*)(ws + 17694720);
    bf16* Wouth = (bf16*)(ws + 19005440);
    bf16* Woutl = (bf16*)(ws + 19398656);
    bf16* Qhi   = (bf16*)(ws + 19791872);
    bf16* Qlo   = (bf16*)(ws + 28180480);
    bf16* Khi   = (bf16*)(ws + 36569088);
    bf16* Klo   = (bf16*)(ws + 44957696);
    bf16* Vt    = (bf16*)(ws + 53346304);

    dim3 blk(256);
    conv_xt_kernel<320><<<dim3(16, 5, 8),  blk, 0, stream>>>(x_q,  Xtq);
    conv_xt_kernel<640><<<dim3(16, 10, 8), blk, 0, stream>>>(x_kv, Xtkv);
    conv_w_kernel<320><<<160, blk, 0, stream>>>(w_q,   Wqh,   Wql,   512);
    conv_w_kernel<640><<<640, blk, 0, stream>>>(w_kv,  Wkvh,  Wkvl,  1024);
    conv_w_kernel<512><<<192, blk, 0, stream>>>(w_out, Wouth, Woutl, 320);

    gemm2t_kernel<320, 1, 0><<<dim3(8, 4, 8), blk, 0, stream>>>(
        Wqh, Wql, Xtq, nullptr, 0, (long)NN * 320, Qhi, Qlo, nullptr, 0.125f);
    gemm2t_kernel<640, 1, 0><<<dim3(8, 4, 8), blk, 0, stream>>>(
        Wkvh, Wkvl, Xtkv, nullptr, 0, (long)NN * 640, Khi, Klo, nullptr, 1.0f);
    gemm2t_kernel<640, 0, 2><<<dim3(4, 8, 8), blk, 0, stream>>>(
        Xtkv, nullptr, Wkvh + (size_t)HID * 640, Wkvl + (size_t)HID * 640,
        (long)NN * 640, 0, Vt, nullptr, nullptr, 1.0f);

    attn_kernel<<<dim3(1024), blk, 0, stream>>>(Qhi, Qlo, Khi, Klo, Vt, Ot);

    gemm2t_kernel<512, 0, 3><<<dim3(3, 8, 8), blk, 0, stream>>>(
        Ot, nullptr, Wouth, Woutl, (long)NN * HID, 0, nullptr, nullptr, out, 1.0f);
}

// Round 5
// 259.283 us; speedup vs baseline: 1.9630x; 1.1126x over previous
//
#include <hip/hip_runtime.h>
#include <math.h>

#define BB   8
#define HH   8
#define DDIM 64
#define NN   1024
#define HID  512
#define COUT 320

typedef float4 f4;
typedef __bf16 bf16;
typedef __attribute__((ext_vector_type(8))) __bf16 bf16x8;
typedef __attribute__((ext_vector_type(4))) __bf16 bf16x4;
typedef __attribute__((ext_vector_type(4))) float f32x4;

#define MFMA16(a,b,c) __builtin_amdgcn_mfma_f32_16x16x32_bf16((a),(b),(c),0,0,0)

// ---------------------------------------------------------------------------
// Prep bodies (same math as rounds 3-4, block coords passed in)
// ---------------------------------------------------------------------------
template<int CIN>
__device__ __forceinline__
void conv_w_body(const float* __restrict__ W, bf16* __restrict__ Wh,
                 bf16* __restrict__ Wl, int rows_valid, int bx)
{
    const int idx = bx * 256 + threadIdx.x;
    const int row = idx / (CIN / 4);
    const int c4  = (idx % (CIN / 4)) * 4;
    f4 v = {0.f, 0.f, 0.f, 0.f};
    if (row < rows_valid) v = *(const f4*)&W[(size_t)row * CIN + c4];
    const float vv[4] = {v.x, v.y, v.z, v.w};
    bf16x4 hv, lv;
#pragma unroll
    for (int e = 0; e < 4; ++e) {
        bf16 hb = (bf16)vv[e];
        hv[e] = hb;
        lv[e] = (bf16)(vv[e] - (float)hb);
    }
    *(bf16x4*)&Wh[(size_t)row * CIN + c4] = hv;
    *(bf16x4*)&Wl[(size_t)row * CIN + c4] = lv;
}

template<int CIN>
__device__ __forceinline__
void conv_xt_body(const float* __restrict__ X, bf16* __restrict__ Xt,
                  float (*Xs)[68], int bx, int by, int bz)
{
    const int n0 = bx * 64;
    const int c0 = by * 64;
    const int t  = threadIdx.x;
    const float* Xb = X + (size_t)bz * CIN * NN;
#pragma unroll
    for (int it = 0; it < 4; ++it) {
        const int r  = it * 16 + (t >> 4);
        const int cc = (t & 15) * 4;
        *(f4*)&Xs[r][cc] = *(const f4*)&Xb[(size_t)(c0 + r) * NN + n0 + cc];
    }
    __syncthreads();
    const int n  = t >> 2;
    const int cb = (t & 3) * 16;
    union { bf16 h[16]; uint4 u[2]; } o;
#pragma unroll
    for (int e = 0; e < 16; ++e) o.h[e] = (bf16)Xs[cb + e][n];
    bf16* dst = Xt + ((size_t)bz * NN + n0 + n) * CIN + c0 + cb;
    *(uint4*)dst = o.u[0];
    *(uint4*)(dst + 8) = o.u[1];
}

// One dispatch for all input conversions. 2912 blocks.
__global__ __launch_bounds__(256)
void prep_kernel(const float* __restrict__ x_q, const float* __restrict__ x_kv,
                 const float* __restrict__ w_q, const float* __restrict__ w_kv,
                 const float* __restrict__ w_out,
                 bf16* __restrict__ Xtq, bf16* __restrict__ Xtkv,
                 bf16* __restrict__ Wqh, bf16* __restrict__ Wql,
                 bf16* __restrict__ Wkvh, bf16* __restrict__ Wkvl,
                 bf16* __restrict__ Wouth, bf16* __restrict__ Woutl)
{
    __shared__ __align__(16) float Xs[64][68];
    const int id = blockIdx.x;
    if (id < 640) {
        const int r = id >> 4;
        conv_xt_body<320>(x_q, Xtq, Xs, id & 15, r % 5, r / 5);
    } else if (id < 1920) {
        const int i = id - 640, r = i >> 4;
        conv_xt_body<640>(x_kv, Xtkv, Xs, i & 15, r % 10, r / 10);
    } else if (id < 2080) {
        conv_w_body<320>(w_q, Wqh, Wql, 512, id - 1920);
    } else if (id < 2720) {
        conv_w_body<640>(w_kv, Wkvh, Wkvl, 1024, id - 2080);
    } else {
        conv_w_body<512>(w_out, Wouth, Woutl, 320, id - 2720);
    }
}

// ---------------------------------------------------------------------------
// Generic 2-term split-bf16 MFMA GEMM body, 128x128 tile, BK=32, 4 waves.
// ---------------------------------------------------------------------------
#define SLOT_A  0
#define SLOT_AL 8192
#define SLOT_B  16384
#define SLOT_BL 24576

template<int K, int ASPLIT, int EPI>
__device__ __forceinline__
void gemm_body(char* lds,
               const bf16* __restrict__ Ah, const bf16* __restrict__ Al,
               const bf16* __restrict__ Bh, const bf16* __restrict__ Bl,
               long a_bstride, long b_bstride,
               bf16* __restrict__ D0, bf16* __restrict__ D1,
               float* __restrict__ Df, float scale,
               int bx, int by, int bz)
{
    const int t  = threadIdx.x;
    const int w  = t >> 6, l = t & 63;
    const int lg = l >> 4, lq = l & 15;
    const int wa = w >> 1, wb = w & 1;
    const int b  = bz;
    const int arow0 = by * 128;
    const int brow0 = bx * 128;

    const bf16* Ab  = Ah + (size_t)b * a_bstride;
    const bf16* Alb = ASPLIT ? (Al + (size_t)b * a_bstride) : (const bf16*)nullptr;
    const bf16* Bb  = Bh + (size_t)b * b_bstride;
    const bf16* Blb = ASPLIT ? (const bf16*)nullptr : (Bl + (size_t)b * b_bstride);

    const int srow = t >> 2;
    const int scg  = (t & 3) ^ ((t >> 3) & 3);
    const int wbyte = srow * 64 + (t & 3) * 16;

    f32x4 acc[4][4];
#pragma unroll
    for (int i = 0; i < 4; ++i)
#pragma unroll
        for (int j = 0; j < 4; ++j) acc[i][j] = (f32x4){0.f, 0.f, 0.f, 0.f};

    constexpr int NK = K / 32;
    uint4 gv[6];

#pragma unroll
    for (int j = 0; j < 2; ++j) {
        const int row = j * 64 + srow;
        const size_t koff = scg * 8;
        gv[j]     = *(const uint4*)(Ab + (size_t)(arow0 + row) * K + koff);
        gv[4 + j] = *(const uint4*)(Bb + (size_t)(brow0 + row) * K + koff);
        gv[2 + j] = ASPLIT ? *(const uint4*)(Alb + (size_t)(arow0 + row) * K + koff)
                           : *(const uint4*)(Blb + (size_t)(brow0 + row) * K + koff);
    }

    for (int ks = 0; ks < NK; ++ks) {
#pragma unroll
        for (int j = 0; j < 2; ++j) {
            const int off = j * 4096 + wbyte;
            *(uint4*)(lds + SLOT_A + off) = gv[j];
            *(uint4*)(lds + SLOT_B + off) = gv[4 + j];
            *(uint4*)(lds + (ASPLIT ? SLOT_AL : SLOT_BL) + off) = gv[2 + j];
        }
        __syncthreads();

        if (ks + 1 < NK) {
            const size_t k0 = (size_t)(ks + 1) * 32 + scg * 8;
#pragma unroll
            for (int j = 0; j < 2; ++j) {
                const int row = j * 64 + srow;
                gv[j]     = *(const uint4*)(Ab + (size_t)(arow0 + row) * K + k0);
                gv[4 + j] = *(const uint4*)(Bb + (size_t)(brow0 + row) * K + k0);
                gv[2 + j] = ASPLIT ? *(const uint4*)(Alb + (size_t)(arow0 + row) * K + k0)
                                   : *(const uint4*)(Blb + (size_t)(brow0 + row) * K + k0);
            }
        }

        bf16x8 a0[4], a1[4], b0[4], b1[4];
#pragma unroll
        for (int m = 0; m < 4; ++m) {
            const int rA = wa * 64 + 16 * m + lq;
            const int offA = rA * 64 + ((lg ^ ((rA >> 1) & 3)) << 4);
            a0[m] = *(const bf16x8*)(lds + SLOT_A + offA);
            if (ASPLIT) a1[m] = *(const bf16x8*)(lds + SLOT_AL + offA);
            const int rB = wb * 64 + 16 * m + lq;
            const int offB = rB * 64 + ((lg ^ ((rB >> 1) & 3)) << 4);
            b0[m] = *(const bf16x8*)(lds + SLOT_B + offB);
            if (!ASPLIT) b1[m] = *(const bf16x8*)(lds + SLOT_BL + offB);
        }
        __builtin_amdgcn_s_setprio(1);
#pragma unroll
        for (int mA = 0; mA < 4; ++mA)
#pragma unroll
            for (int mB = 0; mB < 4; ++mB) {
                acc[mA][mB] = MFMA16(a0[mA], b0[mB], acc[mA][mB]);
                acc[mA][mB] = ASPLIT ? MFMA16(a1[mA], b0[mB], acc[mA][mB])
                                     : MFMA16(a0[mA], b1[mB], acc[mA][mB]);
            }
        __builtin_amdgcn_s_setprio(0);
        __syncthreads();
    }

#pragma unroll
    for (int mA = 0; mA < 4; ++mA)
#pragma unroll
        for (int mB = 0; mB < 4; ++mB) {
            if (EPI <= 1) {
                const int o = arow0 + wa * 64 + 16 * mA + 4 * lg;
                const int i = brow0 + wb * 64 + 16 * mB + lq;
                const int h = o >> 6, d = o & 63;
                const size_t base = ((size_t)((b * HH + h) * NN + i)) * 64 + d;
                bf16x4 hv, lv;
#pragma unroll
                for (int r = 0; r < 4; ++r) {
                    const float v = acc[mA][mB][r] * scale;
                    bf16 hb = (bf16)v;
                    hv[r] = hb;
                    lv[r] = (bf16)(v - (float)hb);
                }
                *(bf16x4*)(D0 + base) = hv;
                *(bf16x4*)(D1 + base) = lv;
            } else if (EPI == 2) {
                const int i = arow0 + wa * 64 + 16 * mA + 4 * lg;
                const int o = brow0 + wb * 64 + 16 * mB + lq;
                const int h = o >> 6, d = o & 63;
                const size_t base = ((size_t)((b * HH + h) * DDIM + d)) * NN + i;
                bf16x4 pv;
#pragma unroll
                for (int r = 0; r < 4; ++r) pv[r] = (bf16)acc[mA][mB][r];
                *(bf16x4*)(D0 + base) = pv;
            } else {
                const int i = arow0 + wa * 64 + 16 * mA + 4 * lg;
                const int o = brow0 + wb * 64 + 16 * mB + lq;
                if (o < COUT)
                    *(f32x4*)(Df + ((size_t)(b * COUT + o)) * NN + i) = acc[mA][mB];
            }
        }
}

// Fused Q/K/V projection: 768 blocks (256 each), wave-uniform branch.
__global__ __launch_bounds__(256)
void gemm_qkv_kernel(const bf16* __restrict__ Xtq, const bf16* __restrict__ Xtkv,
                     const bf16* __restrict__ Wqh, const bf16* __restrict__ Wql,
                     const bf16* __restrict__ Wkvh, const bf16* __restrict__ Wkvl,
                     bf16* __restrict__ Qhi, bf16* __restrict__ Qlo,
                     bf16* __restrict__ Khi, bf16* __restrict__ Klo,
                     bf16* __restrict__ Vt)
{
    __shared__ __align__(16) char lds[32768];
    const int id = blockIdx.x;
    if (id < 256) {
        gemm_body<320, 1, 0>(lds, Wqh, Wql, Xtq, nullptr, 0, (long)NN * 320,
                             Qhi, Qlo, nullptr, 0.125f,
                             id & 7, (id >> 3) & 3, id >> 5);
    } else if (id < 512) {
        const int i = id - 256;
        gemm_body<640, 1, 0>(lds, Wkvh, Wkvl, Xtkv, nullptr, 0, (long)NN * 640,
                             Khi, Klo, nullptr, 1.0f,
                             i & 7, (i >> 3) & 3, i >> 5);
    } else {
        const int i = id - 512;
        gemm_body<640, 0, 2>(lds, Xtkv, nullptr,
                             Wkvh + (size_t)HID * 640, Wkvl + (size_t)HID * 640,
                             (long)NN * 640, 0, Vt, nullptr, nullptr, 1.0f,
                             i & 3, (i >> 2) & 7, i >> 5);
    }
}

__global__ __launch_bounds__(256)
void outproj_kernel(const bf16* __restrict__ Ot,
                    const bf16* __restrict__ Wouth, const bf16* __restrict__ Woutl,
                    float* __restrict__ out)
{
    __shared__ __align__(16) char lds[32768];
    gemm_body<512, 0, 3>(lds, Ot, nullptr, Wouth, Woutl, (long)NN * HID, 0,
                         nullptr, nullptr, out, 1.0f,
                         blockIdx.x, blockIdx.y, blockIdx.z);
}

// ---------------------------------------------------------------------------
// MFMA flash attention. Round-5 change: __launch_bounds__(256,2) gives the
// register allocator a 256-VGPR budget -> no scratch spills (round 2-4 spilled
// ~96B/thread/iter => ~390MB of HBM writeback = the kernel's runtime).
// ---------------------------------------------------------------------------
__global__ __launch_bounds__(256, 2)
void attn_kernel(const bf16* __restrict__ Qhi, const bf16* __restrict__ Qlo,
                 const bf16* __restrict__ Khi, const bf16* __restrict__ Klo,
                 const bf16* __restrict__ Vt,  bf16* __restrict__ Ot)
{
    const int id  = blockIdx.x;
    const int loc = id >> 3;
    const int bh  = (id & 7) * 8 + (loc >> 4);   // 8 bh per XCD
    const int i0  = (loc & 15) * 64;
    const int b   = bh >> 3, h = bh & 7;
    const int t   = threadIdx.x;
    const int w   = t >> 6;
    const int l   = t & 63;
    const int lg  = l >> 4;
    const int lq  = l & 15;

    __shared__ __align__(16) char lds[32768];

    const size_t qbase = ((size_t)(bh * NN) + i0 + w * 16 + lq) * DDIM + lg * 8;
    bf16x8 qh[2], qlo[2];
    qh[0]  = *(const bf16x8*)(Qhi + qbase);
    qh[1]  = *(const bf16x8*)(Qhi + qbase + 32);
    qlo[0] = *(const bf16x8*)(Qlo + qbase);
    qlo[1] = *(const bf16x8*)(Qlo + qbase + 32);

    const int srow = t >> 3;
    const int scc  = t & 7;
    const bf16* pKh = Khi + ((size_t)(bh * NN) + srow) * DDIM + scc * 8;
    const bf16* pKl = Klo + ((size_t)(bh * NN) + srow) * DDIM + scc * 8;
    const bf16* pV  = Vt  + (((size_t)(bh * DDIM) + srow) << 10) + scc * 8;
    const int dwA = srow * 128 + ((scc ^ (srow & 7)) << 4);

    uint4 gv[6];
    gv[0] = *(const uint4*)(pKh);
    gv[1] = *(const uint4*)(pKh + 32 * DDIM);
    gv[2] = *(const uint4*)(pKl);
    gv[3] = *(const uint4*)(pKl + 32 * DDIM);
    gv[4] = *(const uint4*)(pV);
    gv[5] = *(const uint4*)(pV + (32 << 10));

    f32x4 Oa[4];
#pragma unroll
    for (int m = 0; m < 4; ++m) { Oa[m][0]=0.f; Oa[m][1]=0.f; Oa[m][2]=0.f; Oa[m][3]=0.f; }
    float m_run = -INFINITY, l_run = 0.f;

    char* Pw = lds + 24576 + w * 2048;

    for (int jt = 0; jt < 16; ++jt) {
        __syncthreads();
        *(uint4*)(lds +         dwA)        = gv[0];
        *(uint4*)(lds +         dwA + 4096) = gv[1];
        *(uint4*)(lds +  8192 + dwA)        = gv[2];
        *(uint4*)(lds +  8192 + dwA + 4096) = gv[3];
        *(uint4*)(lds + 16384 + dwA)        = gv[4];
        *(uint4*)(lds + 16384 + dwA + 4096) = gv[5];
        __syncthreads();

        if (jt + 1 < 16) {
            pKh += 64 * DDIM; pKl += 64 * DDIM; pV += 64;
            gv[0] = *(const uint4*)(pKh);
            gv[1] = *(const uint4*)(pKh + 32 * DDIM);
            gv[2] = *(const uint4*)(pKl);
            gv[3] = *(const uint4*)(pKl + 32 * DDIM);
            gv[4] = *(const uint4*)(pV);
            gv[5] = *(const uint4*)(pV + (32 << 10));
        }

        f32x4 S[4];
#pragma unroll
        for (int m = 0; m < 4; ++m) {
            f32x4 acc = {0.f, 0.f, 0.f, 0.f};
#pragma unroll
            for (int ks = 0; ks < 2; ++ks) {
                const int row = lq + 16 * m;
                const int ch  = ((lg + 4 * ks) ^ (row & 7)) << 4;
                bf16x8 kh = *(const bf16x8*)(lds + row * 128 + ch);
                bf16x8 kl = *(const bf16x8*)(lds + 8192 + row * 128 + ch);
                __builtin_amdgcn_s_setprio(1);
                acc = MFMA16(kh, qh[ks], acc);
                acc = MFMA16(kh, qlo[ks], acc);
                acc = MFMA16(kl, qh[ks], acc);
                __builtin_amdgcn_s_setprio(0);
            }
            S[m] = acc;
        }

        float tm = S[0][0];
#pragma unroll
        for (int m = 0; m < 4; ++m)
#pragma unroll
            for (int r = 0; r < 4; ++r) tm = fmaxf(tm, S[m][r]);
        tm = fmaxf(tm, __shfl_xor(tm, 16));
        tm = fmaxf(tm, __shfl_xor(tm, 32));
        const float mnew = fmaxf(m_run, tm);
        const float corr = __expf(m_run - mnew);
        float ps[4][4];
        float psum = 0.f;
#pragma unroll
        for (int m = 0; m < 4; ++m)
#pragma unroll
            for (int r = 0; r < 4; ++r) {
                const float p = __expf(S[m][r] - mnew);
                ps[m][r] = p;
                psum += p;
            }
        psum += __shfl_xor(psum, 16);
        psum += __shfl_xor(psum, 32);
        l_run = l_run * corr + psum;
        m_run = mnew;
#pragma unroll
        for (int m = 0; m < 4; ++m)
#pragma unroll
            for (int r = 0; r < 4; ++r) Oa[m][r] *= corr;

#pragma unroll
        for (int f = 0; f < 4; ++f) {
            union { bf16 hh[4]; uint2 u; } pu;
            pu.hh[0] = (bf16)ps[f][0];
            pu.hh[1] = (bf16)ps[f][1];
            pu.hh[2] = (bf16)ps[f][2];
            pu.hh[3] = (bf16)ps[f][3];
            *(uint2*)(Pw + lq * 128 + (((2 * f + (lg >> 1)) ^ (lq & 7)) << 4) + ((lg & 1) << 3)) = pu.u;
        }

#pragma unroll
        for (int ks = 0; ks < 2; ++ks) {
            bf16x8 pb = *(const bf16x8*)(Pw + lq * 128 + (((lg + 4 * ks) ^ (lq & 7)) << 4));
            __builtin_amdgcn_s_setprio(1);
#pragma unroll
            for (int m = 0; m < 4; ++m) {
                const int row = lq + 16 * m;
                bf16x8 va = *(const bf16x8*)(lds + 16384 + row * 128 + (((lg + 4 * ks) ^ (row & 7)) << 4));
                Oa[m] = MFMA16(va, pb, Oa[m]);
            }
            __builtin_amdgcn_s_setprio(0);
        }
    }

    const float inv = 1.0f / l_run;
    const int i = i0 + w * 16 + lq;
    const size_t obase = ((size_t)(b * NN) + i) * HID + h * DDIM;
#pragma unroll
    for (int m = 0; m < 4; ++m) {
        bf16x4 ov;
#pragma unroll
        for (int r = 0; r < 4; ++r) ov[r] = (bf16)(Oa[m][r] * inv);
        *(bf16x4*)(Ot + obase + 16 * m + 4 * lg) = ov;
    }
}

// ---------------------------------------------------------------------------
extern "C" void kernel_launch(void* const* d_in, const int* in_sizes, int n_in,
                              void* d_out, int out_size, void* d_ws, size_t ws_size,
                              hipStream_t stream)
{
    const float* x_q   = (const float*)d_in[0];
    const float* x_kv  = (const float*)d_in[1];
    const float* w_q   = (const float*)d_in[2];
    const float* w_kv  = (const float*)d_in[3];
    const float* w_out = (const float*)d_in[4];
    float* out = (float*)d_out;

    char* ws = (char*)d_ws;
    bf16* Xtq   = (bf16*)(ws + 0);
    bf16* Ot    = (bf16*)(ws + 0);
    bf16* Xtkv  = (bf16*)(ws + 5242880);
    bf16* Wqh   = (bf16*)(ws + 15728640);
    bf16* Wql   = (bf16*)(ws + 16056320);
    bf16* Wkvh  = (bf16*)(ws + 16384000);
    bf16* Wkvl  = (bf16*)(ws + 17694720);
    bf16* Wouth = (bf16*)(ws + 19005440);
    bf16* Woutl = (bf16*)(ws + 19398656);
    bf16* Qhi   = (bf16*)(ws + 19791872);
    bf16* Qlo   = (bf16*)(ws + 28180480);
    bf16* Khi   = (bf16*)(ws + 36569088);
    bf16* Klo   = (bf16*)(ws + 44957696);
    bf16* Vt    = (bf16*)(ws + 53346304);

    dim3 blk(256);
    prep_kernel<<<dim3(2912), blk, 0, stream>>>(x_q, x_kv, w_q, w_kv, w_out,
                                                Xtq, Xtkv, Wqh, Wql, Wkvh, Wkvl,
                                                Wouth, Woutl);
    gemm_qkv_kernel<<<dim3(768), blk, 0, stream>>>(Xtq, Xtkv, Wqh, Wql, Wkvh, Wkvl,
                                                   Qhi, Qlo, Khi, Klo, Vt);
    attn_kernel<<<dim3(1024), blk, 0, stream>>>(Qhi, Qlo, Khi, Klo, Vt, Ot);
    outproj_kernel<<<dim3(3, 8, 8), blk, 0, stream>>>(Ot, Wouth, Woutl, out);
}

// Round 6
// 197.577 us; speedup vs baseline: 2.5760x; 1.3123x over previous
//
#include <hip/hip_runtime.h>
#include <math.h>

#define BB   8
#define HH   8
#define DDIM 64
#define NN   1024
#define HID  512
#define COUT 320

typedef float4 f4;
typedef __bf16 bf16;
typedef __attribute__((ext_vector_type(8))) __bf16 bf16x8;
typedef __attribute__((ext_vector_type(4))) __bf16 bf16x4;
typedef __attribute__((ext_vector_type(4))) float f32x4;

#define MFMA16(a,b,c) __builtin_amdgcn_mfma_f32_16x16x32_bf16((a),(b),(c),0,0,0)

__device__ __forceinline__ void gll16(const bf16* g, char* l) {
    __builtin_amdgcn_global_load_lds(
        (const __attribute__((address_space(1))) void*)g,
        (__attribute__((address_space(3))) void*)l, 16, 0, 0);
}

// ---------------------------------------------------------------------------
// Prep bodies (verified rounds 3-5)
// ---------------------------------------------------------------------------
template<int CIN>
__device__ __forceinline__
void conv_w_body(const float* __restrict__ W, bf16* __restrict__ Wh,
                 bf16* __restrict__ Wl, int rows_valid, int bx)
{
    const int idx = bx * 256 + threadIdx.x;
    const int row = idx / (CIN / 4);
    const int c4  = (idx % (CIN / 4)) * 4;
    f4 v = {0.f, 0.f, 0.f, 0.f};
    if (row < rows_valid) v = *(const f4*)&W[(size_t)row * CIN + c4];
    const float vv[4] = {v.x, v.y, v.z, v.w};
    bf16x4 hv, lv;
#pragma unroll
    for (int e = 0; e < 4; ++e) {
        bf16 hb = (bf16)vv[e];
        hv[e] = hb;
        lv[e] = (bf16)(vv[e] - (float)hb);
    }
    *(bf16x4*)&Wh[(size_t)row * CIN + c4] = hv;
    *(bf16x4*)&Wl[(size_t)row * CIN + c4] = lv;
}

template<int CIN>
__device__ __forceinline__
void conv_xt_body(const float* __restrict__ X, bf16* __restrict__ Xt,
                  float (*Xs)[68], int bx, int by, int bz)
{
    const int n0 = bx * 64;
    const int c0 = by * 64;
    const int t  = threadIdx.x;
    const float* Xb = X + (size_t)bz * CIN * NN;
#pragma unroll
    for (int it = 0; it < 4; ++it) {
        const int r  = it * 16 + (t >> 4);
        const int cc = (t & 15) * 4;
        *(f4*)&Xs[r][cc] = *(const f4*)&Xb[(size_t)(c0 + r) * NN + n0 + cc];
    }
    __syncthreads();
    const int n  = t >> 2;
    const int cb = (t & 3) * 16;
    union { bf16 h[16]; uint4 u[2]; } o;
#pragma unroll
    for (int e = 0; e < 16; ++e) o.h[e] = (bf16)Xs[cb + e][n];
    bf16* dst = Xt + ((size_t)bz * NN + n0 + n) * CIN + c0 + cb;
    *(uint4*)dst = o.u[0];
    *(uint4*)(dst + 8) = o.u[1];
}

__global__ __launch_bounds__(256)
void prep_kernel(const float* __restrict__ x_q, const float* __restrict__ x_kv,
                 const float* __restrict__ w_q, const float* __restrict__ w_kv,
                 const float* __restrict__ w_out,
                 bf16* __restrict__ Xtq, bf16* __restrict__ Xtkv,
                 bf16* __restrict__ Wqh, bf16* __restrict__ Wql,
                 bf16* __restrict__ Wkvh, bf16* __restrict__ Wkvl,
                 bf16* __restrict__ Wouth, bf16* __restrict__ Woutl)
{
    __shared__ __align__(16) float Xs[64][68];
    const int id = blockIdx.x;
    if (id < 640) {
        const int r = id >> 4;
        conv_xt_body<320>(x_q, Xtq, Xs, id & 15, r % 5, r / 5);
    } else if (id < 1920) {
        const int i = id - 640, r = i >> 4;
        conv_xt_body<640>(x_kv, Xtkv, Xs, i & 15, r % 10, r / 10);
    } else if (id < 2080) {
        conv_w_body<320>(w_q, Wqh, Wql, 512, id - 1920);
    } else if (id < 2720) {
        conv_w_body<640>(w_kv, Wkvh, Wkvl, 1024, id - 2080);
    } else {
        conv_w_body<512>(w_out, Wouth, Woutl, 320, id - 2720);
    }
}

// ---------------------------------------------------------------------------
// Generic 2-term split-bf16 MFMA GEMM body, 128x128 tile, BK=32, 4 waves.
// ---------------------------------------------------------------------------
#define SLOT_A  0
#define SLOT_AL 8192
#define SLOT_B  16384
#define SLOT_BL 24576

template<int K, int ASPLIT, int EPI>
__device__ __forceinline__
void gemm_body(char* lds,
               const bf16* __restrict__ Ah, const bf16* __restrict__ Al,
               const bf16* __restrict__ Bh, const bf16* __restrict__ Bl,
               long a_bstride, long b_bstride,
               bf16* __restrict__ D0, bf16* __restrict__ D1,
               float* __restrict__ Df, float scale,
               int bx, int by, int bz)
{
    const int t  = threadIdx.x;
    const int w  = t >> 6, l = t & 63;
    const int lg = l >> 4, lq = l & 15;
    const int wa = w >> 1, wb = w & 1;
    const int b  = bz;
    const int arow0 = by * 128;
    const int brow0 = bx * 128;

    const bf16* Ab  = Ah + (size_t)b * a_bstride;
    const bf16* Alb = ASPLIT ? (Al + (size_t)b * a_bstride) : (const bf16*)nullptr;
    const bf16* Bb  = Bh + (size_t)b * b_bstride;
    const bf16* Blb = ASPLIT ? (const bf16*)nullptr : (Bl + (size_t)b * b_bstride);

    const int srow = t >> 2;
    const int scg  = (t & 3) ^ ((t >> 3) & 3);
    const int wbyte = srow * 64 + (t & 3) * 16;

    f32x4 acc[4][4];
#pragma unroll
    for (int i = 0; i < 4; ++i)
#pragma unroll
        for (int j = 0; j < 4; ++j) acc[i][j] = (f32x4){0.f, 0.f, 0.f, 0.f};

    constexpr int NK = K / 32;
    uint4 gv[6];

#pragma unroll
    for (int j = 0; j < 2; ++j) {
        const int row = j * 64 + srow;
        const size_t koff = scg * 8;
        gv[j]     = *(const uint4*)(Ab + (size_t)(arow0 + row) * K + koff);
        gv[4 + j] = *(const uint4*)(Bb + (size_t)(brow0 + row) * K + koff);
        gv[2 + j] = ASPLIT ? *(const uint4*)(Alb + (size_t)(arow0 + row) * K + koff)
                           : *(const uint4*)(Blb + (size_t)(brow0 + row) * K + koff);
    }

    for (int ks = 0; ks < NK; ++ks) {
#pragma unroll
        for (int j = 0; j < 2; ++j) {
            const int off = j * 4096 + wbyte;
            *(uint4*)(lds + SLOT_A + off) = gv[j];
            *(uint4*)(lds + SLOT_B + off) = gv[4 + j];
            *(uint4*)(lds + (ASPLIT ? SLOT_AL : SLOT_BL) + off) = gv[2 + j];
        }
        __syncthreads();

        if (ks + 1 < NK) {
            const size_t k0 = (size_t)(ks + 1) * 32 + scg * 8;
#pragma unroll
            for (int j = 0; j < 2; ++j) {
                const int row = j * 64 + srow;
                gv[j]     = *(const uint4*)(Ab + (size_t)(arow0 + row) * K + k0);
                gv[4 + j] = *(const uint4*)(Bb + (size_t)(brow0 + row) * K + k0);
                gv[2 + j] = ASPLIT ? *(const uint4*)(Alb + (size_t)(arow0 + row) * K + k0)
                                   : *(const uint4*)(Blb + (size_t)(brow0 + row) * K + k0);
            }
        }

        bf16x8 a0[4], a1[4], b0[4], b1[4];
#pragma unroll
        for (int m = 0; m < 4; ++m) {
            const int rA = wa * 64 + 16 * m + lq;
            const int offA = rA * 64 + ((lg ^ ((rA >> 1) & 3)) << 4);
            a0[m] = *(const bf16x8*)(lds + SLOT_A + offA);
            if (ASPLIT) a1[m] = *(const bf16x8*)(lds + SLOT_AL + offA);
            const int rB = wb * 64 + 16 * m + lq;
            const int offB = rB * 64 + ((lg ^ ((rB >> 1) & 3)) << 4);
            b0[m] = *(const bf16x8*)(lds + SLOT_B + offB);
            if (!ASPLIT) b1[m] = *(const bf16x8*)(lds + SLOT_BL + offB);
        }
        __builtin_amdgcn_s_setprio(1);
#pragma unroll
        for (int mA = 0; mA < 4; ++mA)
#pragma unroll
            for (int mB = 0; mB < 4; ++mB) {
                acc[mA][mB] = MFMA16(a0[mA], b0[mB], acc[mA][mB]);
                acc[mA][mB] = ASPLIT ? MFMA16(a1[mA], b0[mB], acc[mA][mB])
                                     : MFMA16(a0[mA], b1[mB], acc[mA][mB]);
            }
        __builtin_amdgcn_s_setprio(0);
        __syncthreads();
    }

#pragma unroll
    for (int mA = 0; mA < 4; ++mA)
#pragma unroll
        for (int mB = 0; mB < 4; ++mB) {
            if (EPI <= 1) {
                const int o = arow0 + wa * 64 + 16 * mA + 4 * lg;
                const int i = brow0 + wb * 64 + 16 * mB + lq;
                const int h = o >> 6, d = o & 63;
                const size_t base = ((size_t)((b * HH + h) * NN + i)) * 64 + d;
                bf16x4 hv, lv;
#pragma unroll
                for (int r = 0; r < 4; ++r) {
                    const float v = acc[mA][mB][r] * scale;
                    bf16 hb = (bf16)v;
                    hv[r] = hb;
                    lv[r] = (bf16)(v - (float)hb);
                }
                *(bf16x4*)(D0 + base) = hv;
                *(bf16x4*)(D1 + base) = lv;
            } else if (EPI == 2) {
                const int i = arow0 + wa * 64 + 16 * mA + 4 * lg;
                const int o = brow0 + wb * 64 + 16 * mB + lq;
                const int h = o >> 6, d = o & 63;
                const size_t base = ((size_t)((b * HH + h) * DDIM + d)) * NN + i;
                bf16x4 pv;
#pragma unroll
                for (int r = 0; r < 4; ++r) pv[r] = (bf16)acc[mA][mB][r];
                *(bf16x4*)(D0 + base) = pv;
            } else {
                const int i = arow0 + wa * 64 + 16 * mA + 4 * lg;
                const int o = brow0 + wb * 64 + 16 * mB + lq;
                if (o < COUT)
                    *(f32x4*)(Df + ((size_t)(b * COUT + o)) * NN + i) = acc[mA][mB];
            }
        }
}

__global__ __launch_bounds__(256)
void gemm_qkv_kernel(const bf16* __restrict__ Xtq, const bf16* __restrict__ Xtkv,
                     const bf16* __restrict__ Wqh, const bf16* __restrict__ Wql,
                     const bf16* __restrict__ Wkvh, const bf16* __restrict__ Wkvl,
                     bf16* __restrict__ Qhi, bf16* __restrict__ Qlo,
                     bf16* __restrict__ Khi, bf16* __restrict__ Klo,
                     bf16* __restrict__ Vt)
{
    __shared__ __align__(16) char lds[32768];
    const int id = blockIdx.x;
    if (id < 256) {
        gemm_body<320, 1, 0>(lds, Wqh, Wql, Xtq, nullptr, 0, (long)NN * 320,
                             Qhi, Qlo, nullptr, 0.125f,
                             id & 7, (id >> 3) & 3, id >> 5);
    } else if (id < 512) {
        const int i = id - 256;
        gemm_body<640, 1, 0>(lds, Wkvh, Wkvl, Xtkv, nullptr, 0, (long)NN * 640,
                             Khi, Klo, nullptr, 1.0f,
                             i & 7, (i >> 3) & 3, i >> 5);
    } else {
        const int i = id - 512;
        gemm_body<640, 0, 2>(lds, Xtkv, nullptr,
                             Wkvh + (size_t)HID * 640, Wkvl + (size_t)HID * 640,
                             (long)NN * 640, 0, Vt, nullptr, nullptr, 1.0f,
                             i & 3, (i >> 2) & 7, i >> 5);
    }
}

__global__ __launch_bounds__(256)
void outproj_kernel(const bf16* __restrict__ Ot,
                    const bf16* __restrict__ Wouth, const bf16* __restrict__ Woutl,
                    float* __restrict__ out)
{
    __shared__ __align__(16) char lds[32768];
    gemm_body<512, 0, 3>(lds, Ot, nullptr, Wouth, Woutl, (long)NN * HID, 0,
                         nullptr, nullptr, out, 1.0f,
                         blockIdx.x, blockIdx.y, blockIdx.z);
}

// ---------------------------------------------------------------------------
// MFMA flash attention, round 6: K/V staged HBM->LDS via global_load_lds
// (no staging registers -> nothing to spill), double-buffered (2x24KB),
// counted-vmcnt 2-phase pipeline with raw s_barrier. LDS writes are linear;
// the bank swizzle (chunk ^ (row&7)) is applied to the per-lane GLOBAL source
// address; read side identical to the verified rounds 2-5.
// LDS: [0,24576) buf0 {Khi,Klo,V}; [24576,49152) buf1; [49152,57344) P.
// ---------------------------------------------------------------------------
__global__ __launch_bounds__(256, 2)
void attn_kernel(const bf16* __restrict__ Qhi, const bf16* __restrict__ Qlo,
                 const bf16* __restrict__ Khi, const bf16* __restrict__ Klo,
                 const bf16* __restrict__ Vt,  bf16* __restrict__ Ot)
{
    const int id  = blockIdx.x;
    const int loc = id >> 3;
    const int bh  = (id & 7) * 8 + (loc >> 4);   // 8 bh per XCD
    const int i0  = (loc & 15) * 64;
    const int b   = bh >> 3, h = bh & 7;
    const int t   = threadIdx.x;
    const int w   = t >> 6;
    const int l   = t & 63;
    const int lg  = l >> 4;
    const int lq  = l & 15;

    __shared__ __align__(16) char lds[57344];

    // Q fragments (registers, loaded once)
    const size_t qbase = ((size_t)(bh * NN) + i0 + w * 16 + lq) * DDIM + lg * 8;
    bf16x8 qh[2], qlo[2];
    qh[0]  = *(const bf16x8*)(Qhi + qbase);
    qh[1]  = *(const bf16x8*)(Qhi + qbase + 32);
    qlo[0] = *(const bf16x8*)(Qlo + qbase);
    qlo[1] = *(const bf16x8*)(Qlo + qbase + 32);

    // per-lane pre-swizzled global sources: wave w stages rows [16w,16w+16)
    // of each tile; lane l covers row 16w+(l>>3), slot-chunk l&7, whose
    // source chunk is (l&7)^(l>>3)  (involution of the read swizzle).
    const int l8 = l >> 3;
    const int cw = (l & 7) ^ l8;
    const bf16* KhS = Khi + ((size_t)(bh * NN) + 16 * w + l8) * DDIM + cw * 8;
    const bf16* KlS = Klo + ((size_t)(bh * NN) + 16 * w + l8) * DDIM + cw * 8;
    const bf16* VS  = Vt  + (((size_t)(bh * DDIM) + 16 * w + l8) << 10) + cw * 8;
    char* const Lw = lds + (w << 11);   // wave's linear LDS slice base (per region)

    f32x4 Oa[4];
#pragma unroll
    for (int m = 0; m < 4; ++m) { Oa[m][0]=0.f; Oa[m][1]=0.f; Oa[m][2]=0.f; Oa[m][3]=0.f; }
    float m_run = -INFINITY, l_run = 0.f;

    char* Pw = lds + 49152 + w * 2048;

    // prologue: issue tile 0 into buf 0
    {
        gll16(KhS,        Lw);
        gll16(KhS + 512,  Lw + 1024);
        gll16(KlS,        Lw + 8192);
        gll16(KlS + 512,  Lw + 8192 + 1024);
        gll16(VS,         Lw + 16384);
        gll16(VS + 8192,  Lw + 16384 + 1024);
    }

    for (int jt = 0; jt < 16; ++jt) {
        const int p = jt & 1;
        if (jt < 15) {
            // issue next tile into the other buffer (its readers finished at
            // the trailing barrier of the previous iteration)
            char* B = Lw + 24576 * (p ^ 1);
            const bf16* kh = KhS + ((jt + 1) << 12);
            const bf16* kl = KlS + ((jt + 1) << 12);
            const bf16* vs = VS + ((jt + 1) << 6);
            gll16(kh,        B);
            gll16(kh + 512,  B + 1024);
            gll16(kl,        B + 8192);
            gll16(kl + 512,  B + 8192 + 1024);
            gll16(vs,        B + 16384);
            gll16(vs + 8192, B + 16384 + 1024);
            asm volatile("s_waitcnt vmcnt(6)" ::: "memory");
        } else {
            asm volatile("s_waitcnt vmcnt(0)" ::: "memory");
        }
        __builtin_amdgcn_s_barrier();
        __builtin_amdgcn_sched_barrier(0);

        char* buf = lds + 24576 * p;

        // ---- St = K·Q^T (rows j, cols q); split 3-term ----
        f32x4 S[4];
#pragma unroll
        for (int m = 0; m < 4; ++m) {
            f32x4 acc = {0.f, 0.f, 0.f, 0.f};
#pragma unroll
            for (int ks = 0; ks < 2; ++ks) {
                const int row = lq + 16 * m;
                const int ch  = ((lg + 4 * ks) ^ (row & 7)) << 4;
                bf16x8 kh = *(const bf16x8*)(buf + row * 128 + ch);
                bf16x8 kl = *(const bf16x8*)(buf + 8192 + row * 128 + ch);
                __builtin_amdgcn_s_setprio(1);
                acc = MFMA16(kh, qh[ks], acc);
                acc = MFMA16(kh, qlo[ks], acc);
                acc = MFMA16(kl, qh[ks], acc);
                __builtin_amdgcn_s_setprio(0);
            }
            S[m] = acc;
        }

        // ---- online softmax: lane holds 16 j's for q = lq ----
        float tm = S[0][0];
#pragma unroll
        for (int m = 0; m < 4; ++m)
#pragma unroll
            for (int r = 0; r < 4; ++r) tm = fmaxf(tm, S[m][r]);
        tm = fmaxf(tm, __shfl_xor(tm, 16));
        tm = fmaxf(tm, __shfl_xor(tm, 32));
        const float mnew = fmaxf(m_run, tm);
        const float corr = __expf(m_run - mnew);
        float ps[4][4];
        float psum = 0.f;
#pragma unroll
        for (int m = 0; m < 4; ++m)
#pragma unroll
            for (int r = 0; r < 4; ++r) {
                const float p2 = __expf(S[m][r] - mnew);
                ps[m][r] = p2;
                psum += p2;
            }
        psum += __shfl_xor(psum, 16);
        psum += __shfl_xor(psum, 32);
        l_run = l_run * corr + psum;
        m_run = mnew;
#pragma unroll
        for (int m = 0; m < 4; ++m)
#pragma unroll
            for (int r = 0; r < 4; ++r) Oa[m][r] *= corr;

        // ---- P -> per-wave LDS (bf16) ----
#pragma unroll
        for (int f = 0; f < 4; ++f) {
            union { bf16 hh[4]; uint2 u; } pu;
            pu.hh[0] = (bf16)ps[f][0];
            pu.hh[1] = (bf16)ps[f][1];
            pu.hh[2] = (bf16)ps[f][2];
            pu.hh[3] = (bf16)ps[f][3];
            *(uint2*)(Pw + lq * 128 + (((2 * f + (lg >> 1)) ^ (lq & 7)) << 4) + ((lg & 1) << 3)) = pu.u;
        }

        // ---- Ot += Vt · Pt ----
#pragma unroll
        for (int ks = 0; ks < 2; ++ks) {
            bf16x8 pb = *(const bf16x8*)(Pw + lq * 128 + (((lg + 4 * ks) ^ (lq & 7)) << 4));
            __builtin_amdgcn_s_setprio(1);
#pragma unroll
            for (int m = 0; m < 4; ++m) {
                const int row = lq + 16 * m;
                bf16x8 va = *(const bf16x8*)(buf + 16384 + row * 128 + (((lg + 4 * ks) ^ (row & 7)) << 4));
                Oa[m] = MFMA16(va, pb, Oa[m]);
            }
            __builtin_amdgcn_s_setprio(0);
        }

        asm volatile("s_waitcnt lgkmcnt(0)" ::: "memory");
        __builtin_amdgcn_s_barrier();
        __builtin_amdgcn_sched_barrier(0);
    }

    const float inv = 1.0f / l_run;
    const int i = i0 + w * 16 + lq;
    const size_t obase = ((size_t)(b * NN) + i) * HID + h * DDIM;
#pragma unroll
    for (int m = 0; m < 4; ++m) {
        bf16x4 ov;
#pragma unroll
        for (int r = 0; r < 4; ++r) ov[r] = (bf16)(Oa[m][r] * inv);
        *(bf16x4*)(Ot + obase + 16 * m + 4 * lg) = ov;
    }
}

// ---------------------------------------------------------------------------
extern "C" void kernel_launch(void* const* d_in, const int* in_sizes, int n_in,
                              void* d_out, int out_size, void* d_ws, size_t ws_size,
                              hipStream_t stream)
{
    const float* x_q   = (const float*)d_in[0];
    const float* x_kv  = (const float*)d_in[1];
    const float* w_q   = (const float*)d_in[2];
    const float* w_kv  = (const float*)d_in[3];
    const float* w_out = (const float*)d_in[4];
    float* out = (float*)d_out;

    char* ws = (char*)d_ws;
    bf16* Xtq   = (bf16*)(ws + 0);
    bf16* Ot    = (bf16*)(ws + 0);
    bf16* Xtkv  = (bf16*)(ws + 5242880);
    bf16* Wqh   = (bf16*)(ws + 15728640);
    bf16* Wql   = (bf16*)(ws + 16056320);
    bf16* Wkvh  = (bf16*)(ws + 16384000);
    bf16* Wkvl  = (bf16*)(ws + 17694720);
    bf16* Wouth = (bf16*)(ws + 19005440);
    bf16* Woutl = (bf16*)(ws + 19398656);
    bf16* Qhi   = (bf16*)(ws + 19791872);
    bf16* Qlo   = (bf16*)(ws + 28180480);
    bf16* Khi   = (bf16*)(ws + 36569088);
    bf16* Klo   = (bf16*)(ws + 44957696);
    bf16* Vt    = (bf16*)(ws + 53346304);

    dim3 blk(256);
    prep_kernel<<<dim3(2912), blk, 0, stream>>>(x_q, x_kv, w_q, w_kv, w_out,
                                                Xtq, Xtkv, Wqh, Wql, Wkvh, Wkvl,
                                                Wouth, Woutl);
    gemm_qkv_kernel<<<dim3(768), blk, 0, stream>>>(Xtq, Xtkv, Wqh, Wql, Wkvh, Wkvl,
                                                   Qhi, Qlo, Khi, Klo, Vt);
    attn_kernel<<<dim3(1024), blk, 0, stream>>>(Qhi, Qlo, Khi, Klo, Vt, Ot);
    outproj_kernel<<<dim3(3, 8, 8), blk, 0, stream>>>(Ot, Wouth, Woutl, out);
}

// Round 7
// 119.471 us; speedup vs baseline: 4.2601x; 1.6538x over previous
//
#include <hip/hip_runtime.h>
#include <math.h>

#define BB   8
#define HH   8
#define DDIM 64
#define NN   1024
#define HID  512
#define COUT 320

typedef float4 f4;
typedef __bf16 bf16;
typedef __attribute__((ext_vector_type(8))) __bf16 bf16x8;
typedef __attribute__((ext_vector_type(4))) __bf16 bf16x4;
typedef __attribute__((ext_vector_type(4))) float f32x4;

#define MFMA16(a,b,c) __builtin_amdgcn_mfma_f32_16x16x32_bf16((a),(b),(c),0,0,0)

__device__ __forceinline__ void gll16(const bf16* g, char* l) {
    __builtin_amdgcn_global_load_lds(
        (const __attribute__((address_space(1))) void*)g,
        (__attribute__((address_space(3))) void*)l, 16, 0, 0);
}

// ---------------------------------------------------------------------------
// Prep bodies (verified rounds 3-6)
// ---------------------------------------------------------------------------
template<int CIN>
__device__ __forceinline__
void conv_w_body(const float* __restrict__ W, bf16* __restrict__ Wh,
                 bf16* __restrict__ Wl, int rows_valid, int bx)
{
    const int idx = bx * 256 + threadIdx.x;
    const int row = idx / (CIN / 4);
    const int c4  = (idx % (CIN / 4)) * 4;
    f4 v = {0.f, 0.f, 0.f, 0.f};
    if (row < rows_valid) v = *(const f4*)&W[(size_t)row * CIN + c4];
    const float vv[4] = {v.x, v.y, v.z, v.w};
    bf16x4 hv, lv;
#pragma unroll
    for (int e = 0; e < 4; ++e) {
        bf16 hb = (bf16)vv[e];
        hv[e] = hb;
        lv[e] = (bf16)(vv[e] - (float)hb);
    }
    *(bf16x4*)&Wh[(size_t)row * CIN + c4] = hv;
    *(bf16x4*)&Wl[(size_t)row * CIN + c4] = lv;
}

template<int CIN>
__device__ __forceinline__
void conv_xt_body(const float* __restrict__ X, bf16* __restrict__ Xt,
                  float (*Xs)[68], int bx, int by, int bz)
{
    const int n0 = bx * 64;
    const int c0 = by * 64;
    const int t  = threadIdx.x;
    const float* Xb = X + (size_t)bz * CIN * NN;
#pragma unroll
    for (int it = 0; it < 4; ++it) {
        const int r  = it * 16 + (t >> 4);
        const int cc = (t & 15) * 4;
        *(f4*)&Xs[r][cc] = *(const f4*)&Xb[(size_t)(c0 + r) * NN + n0 + cc];
    }
    __syncthreads();
    const int n  = t >> 2;
    const int cb = (t & 3) * 16;
    union { bf16 h[16]; uint4 u[2]; } o;
#pragma unroll
    for (int e = 0; e < 16; ++e) o.h[e] = (bf16)Xs[cb + e][n];
    bf16* dst = Xt + ((size_t)bz * NN + n0 + n) * CIN + c0 + cb;
    *(uint4*)dst = o.u[0];
    *(uint4*)(dst + 8) = o.u[1];
}

__global__ __launch_bounds__(256)
void prep_kernel(const float* __restrict__ x_q, const float* __restrict__ x_kv,
                 const float* __restrict__ w_q, const float* __restrict__ w_kv,
                 const float* __restrict__ w_out,
                 bf16* __restrict__ Xtq, bf16* __restrict__ Xtkv,
                 bf16* __restrict__ Wqh, bf16* __restrict__ Wql,
                 bf16* __restrict__ Wkvh, bf16* __restrict__ Wkvl,
                 bf16* __restrict__ Wouth, bf16* __restrict__ Woutl)
{
    __shared__ __align__(16) float Xs[64][68];
    const int id = blockIdx.x;
    if (id < 640) {
        const int r = id >> 4;
        conv_xt_body<320>(x_q, Xtq, Xs, id & 15, r % 5, r / 5);
    } else if (id < 1920) {
        const int i = id - 640, r = i >> 4;
        conv_xt_body<640>(x_kv, Xtkv, Xs, i & 15, r % 10, r / 10);
    } else if (id < 2080) {
        conv_w_body<320>(w_q, Wqh, Wql, 512, id - 1920);
    } else if (id < 2720) {
        conv_w_body<640>(w_kv, Wkvh, Wkvl, 1024, id - 2080);
    } else {
        conv_w_body<512>(w_out, Wouth, Woutl, 320, id - 2720);
    }
}

// ---------------------------------------------------------------------------
// 2-term split-bf16 MFMA GEMM body, 128x128 tile, BK=32, 4 waves (2x2).
// Round-7: staging via global_load_lds (zero staging registers -> no spill),
// double-buffered LDS (2 x 24KB), counted vmcnt(6) 2-phase pipeline.
// LDS per buffer: [0,8K) A-hi, [8K,16K) X (=A-lo if ASPLIT else B-lo),
// [16K,24K) B-hi. Swizzle (chunk ^ ((row>>1)&3)) applied on the per-lane
// GLOBAL source; LDS writes linear; read side identical to rounds 3-6.
// Wave w, call j stages rows [64j+16w, +16): lds bytes (4j+w)*1024.
// ---------------------------------------------------------------------------
template<int K, int ASPLIT, int EPI>
__device__ __forceinline__
void gemm_body(char* lds,
               const bf16* __restrict__ Ah, const bf16* __restrict__ Al,
               const bf16* __restrict__ Bh, const bf16* __restrict__ Bl,
               long a_bstride, long b_bstride,
               bf16* __restrict__ D0, bf16* __restrict__ D1,
               float* __restrict__ Df, float scale,
               int bx, int by, int bz)
{
    const int t  = threadIdx.x;
    const int w  = t >> 6, l = t & 63;
    const int lg = l >> 4, lq = l & 15;
    const int wa = w >> 1, wb = w & 1;
    const int arow0 = by * 128;
    const int brow0 = bx * 128;

    const bf16* Ab = Ah + (size_t)bz * a_bstride;
    const bf16* Xb = ASPLIT ? (Al + (size_t)bz * a_bstride)
                            : (Bl + (size_t)bz * b_bstride);
    const bf16* Bb = Bh + (size_t)bz * b_bstride;

    // per-lane staging source (j=0 row); swizzled chunk = (l&3) ^ ((l>>3)&3)
    const int srow = 16 * w + (l >> 2);
    const int cw   = (l & 3) ^ ((l >> 3) & 3);
    const bf16* pA = Ab + (size_t)(arow0 + srow) * K + cw * 8;
    const bf16* pX = Xb + (size_t)((ASPLIT ? arow0 : brow0) + srow) * K + cw * 8;
    const bf16* pB = Bb + (size_t)(brow0 + srow) * K + cw * 8;
    const int woff = w * 1024;

    f32x4 acc[4][4];
#pragma unroll
    for (int i = 0; i < 4; ++i)
#pragma unroll
        for (int j = 0; j < 4; ++j) acc[i][j] = (f32x4){0.f, 0.f, 0.f, 0.f};

    constexpr int NK = K / 32;

#define GEMM_ISSUE(ks, pbuf)                                          \
    {                                                                 \
        char* Bd = lds + (pbuf) * 24576 + woff;                       \
        const int ko = (ks) * 32;                                     \
        gll16(pA + ko,          Bd);                                  \
        gll16(pA + 64 * K + ko, Bd + 4096);                           \
        gll16(pX + ko,          Bd + 8192);                           \
        gll16(pX + 64 * K + ko, Bd + 8192 + 4096);                    \
        gll16(pB + ko,          Bd + 16384);                          \
        gll16(pB + 64 * K + ko, Bd + 16384 + 4096);                   \
    }

    GEMM_ISSUE(0, 0)

    for (int ks = 0; ks < NK; ++ks) {
        const int p = ks & 1;
        if (ks + 1 < NK) {
            GEMM_ISSUE(ks + 1, p ^ 1)
            asm volatile("s_waitcnt vmcnt(6)" ::: "memory");
        } else {
            asm volatile("s_waitcnt vmcnt(0)" ::: "memory");
        }
        __builtin_amdgcn_s_barrier();
        __builtin_amdgcn_sched_barrier(0);

        char* buf = lds + p * 24576;
        bf16x8 a0[4], a1[4], b0[4], b1[4];
#pragma unroll
        for (int m = 0; m < 4; ++m) {
            const int rA = wa * 64 + 16 * m + lq;
            const int offA = rA * 64 + ((lg ^ ((rA >> 1) & 3)) << 4);
            a0[m] = *(const bf16x8*)(buf + offA);
            if (ASPLIT) a1[m] = *(const bf16x8*)(buf + 8192 + offA);
            const int rB = wb * 64 + 16 * m + lq;
            const int offB = rB * 64 + ((lg ^ ((rB >> 1) & 3)) << 4);
            b0[m] = *(const bf16x8*)(buf + 16384 + offB);
            if (!ASPLIT) b1[m] = *(const bf16x8*)(buf + 8192 + offB);
        }
        __builtin_amdgcn_s_setprio(1);
#pragma unroll
        for (int mA = 0; mA < 4; ++mA)
#pragma unroll
            for (int mB = 0; mB < 4; ++mB) {
                acc[mA][mB] = MFMA16(a0[mA], b0[mB], acc[mA][mB]);
                acc[mA][mB] = ASPLIT ? MFMA16(a1[mA], b0[mB], acc[mA][mB])
                                     : MFMA16(a0[mA], b1[mB], acc[mA][mB]);
            }
        __builtin_amdgcn_s_setprio(0);
        asm volatile("s_waitcnt lgkmcnt(0)" ::: "memory");
        __builtin_amdgcn_s_barrier();
        __builtin_amdgcn_sched_barrier(0);
    }
#undef GEMM_ISSUE

#pragma unroll
    for (int mA = 0; mA < 4; ++mA)
#pragma unroll
        for (int mB = 0; mB < 4; ++mB) {
            if (EPI <= 1) {
                const int o = arow0 + wa * 64 + 16 * mA + 4 * lg;
                const int i = brow0 + wb * 64 + 16 * mB + lq;
                const int h = o >> 6, d = o & 63;
                const size_t base = ((size_t)((bz * HH + h) * NN + i)) * 64 + d;
                bf16x4 hv, lv;
#pragma unroll
                for (int r = 0; r < 4; ++r) {
                    const float v = acc[mA][mB][r] * scale;
                    bf16 hb = (bf16)v;
                    hv[r] = hb;
                    lv[r] = (bf16)(v - (float)hb);
                }
                *(bf16x4*)(D0 + base) = hv;
                *(bf16x4*)(D1 + base) = lv;
            } else if (EPI == 2) {
                const int i = arow0 + wa * 64 + 16 * mA + 4 * lg;
                const int o = brow0 + wb * 64 + 16 * mB + lq;
                const int h = o >> 6, d = o & 63;
                const size_t base = ((size_t)((bz * HH + h) * DDIM + d)) * NN + i;
                bf16x4 pv;
#pragma unroll
                for (int r = 0; r < 4; ++r) pv[r] = (bf16)acc[mA][mB][r];
                *(bf16x4*)(D0 + base) = pv;
            } else {
                const int i = arow0 + wa * 64 + 16 * mA + 4 * lg;
                const int o = brow0 + wb * 64 + 16 * mB + lq;
                if (o < COUT)
                    *(f32x4*)(Df + ((size_t)(bz * COUT + o)) * NN + i) = acc[mA][mB];
            }
        }
}

__global__ __launch_bounds__(256, 2)
void gemm_qkv_kernel(const bf16* __restrict__ Xtq, const bf16* __restrict__ Xtkv,
                     const bf16* __restrict__ Wqh, const bf16* __restrict__ Wql,
                     const bf16* __restrict__ Wkvh, const bf16* __restrict__ Wkvl,
                     bf16* __restrict__ Qhi, bf16* __restrict__ Qlo,
                     bf16* __restrict__ Khi, bf16* __restrict__ Klo,
                     bf16* __restrict__ Vt)
{
    __shared__ __align__(16) char lds[49152];
    const int id = blockIdx.x;
    if (id < 256) {
        gemm_body<320, 1, 0>(lds, Wqh, Wql, Xtq, nullptr, 0, (long)NN * 320,
                             Qhi, Qlo, nullptr, 0.125f,
                             id & 7, (id >> 3) & 3, id >> 5);
    } else if (id < 512) {
        const int i = id - 256;
        gemm_body<640, 1, 0>(lds, Wkvh, Wkvl, Xtkv, nullptr, 0, (long)NN * 640,
                             Khi, Klo, nullptr, 1.0f,
                             i & 7, (i >> 3) & 3, i >> 5);
    } else {
        const int i = id - 512;
        gemm_body<640, 0, 2>(lds, Xtkv, nullptr,
                             Wkvh + (size_t)HID * 640, Wkvl + (size_t)HID * 640,
                             (long)NN * 640, 0, Vt, nullptr, nullptr, 1.0f,
                             i & 3, (i >> 2) & 7, i >> 5);
    }
}

__global__ __launch_bounds__(256, 2)
void outproj_kernel(const bf16* __restrict__ Ot,
                    const bf16* __restrict__ Wouth, const bf16* __restrict__ Woutl,
                    float* __restrict__ out)
{
    __shared__ __align__(16) char lds[49152];
    gemm_body<512, 0, 3>(lds, Ot, nullptr, Wouth, Woutl, (long)NN * HID, 0,
                         nullptr, nullptr, out, 1.0f,
                         blockIdx.x, blockIdx.y, blockIdx.z);
}

// ---------------------------------------------------------------------------
// MFMA flash attention (round-6 verified: gll16 staging, dbuf, counted vmcnt)
// ---------------------------------------------------------------------------
__global__ __launch_bounds__(256, 2)
void attn_kernel(const bf16* __restrict__ Qhi, const bf16* __restrict__ Qlo,
                 const bf16* __restrict__ Khi, const bf16* __restrict__ Klo,
                 const bf16* __restrict__ Vt,  bf16* __restrict__ Ot)
{
    const int id  = blockIdx.x;
    const int loc = id >> 3;
    const int bh  = (id & 7) * 8 + (loc >> 4);   // 8 bh per XCD
    const int i0  = (loc & 15) * 64;
    const int b   = bh >> 3, h = bh & 7;
    const int t   = threadIdx.x;
    const int w   = t >> 6;
    const int l   = t & 63;
    const int lg  = l >> 4;
    const int lq  = l & 15;

    __shared__ __align__(16) char lds[57344];

    const size_t qbase = ((size_t)(bh * NN) + i0 + w * 16 + lq) * DDIM + lg * 8;
    bf16x8 qh[2], qlo[2];
    qh[0]  = *(const bf16x8*)(Qhi + qbase);
    qh[1]  = *(const bf16x8*)(Qhi + qbase + 32);
    qlo[0] = *(const bf16x8*)(Qlo + qbase);
    qlo[1] = *(const bf16x8*)(Qlo + qbase + 32);

    const int l8 = l >> 3;
    const int cw = (l & 7) ^ l8;
    const bf16* KhS = Khi + ((size_t)(bh * NN) + 16 * w + l8) * DDIM + cw * 8;
    const bf16* KlS = Klo + ((size_t)(bh * NN) + 16 * w + l8) * DDIM + cw * 8;
    const bf16* VS  = Vt  + (((size_t)(bh * DDIM) + 16 * w + l8) << 10) + cw * 8;
    char* const Lw = lds + (w << 11);

    f32x4 Oa[4];
#pragma unroll
    for (int m = 0; m < 4; ++m) { Oa[m][0]=0.f; Oa[m][1]=0.f; Oa[m][2]=0.f; Oa[m][3]=0.f; }
    float m_run = -INFINITY, l_run = 0.f;

    char* Pw = lds + 49152 + w * 2048;

    {
        gll16(KhS,        Lw);
        gll16(KhS + 512,  Lw + 1024);
        gll16(KlS,        Lw + 8192);
        gll16(KlS + 512,  Lw + 8192 + 1024);
        gll16(VS,         Lw + 16384);
        gll16(VS + 8192,  Lw + 16384 + 1024);
    }

    for (int jt = 0; jt < 16; ++jt) {
        const int p = jt & 1;
        if (jt < 15) {
            char* B = Lw + 24576 * (p ^ 1);
            const bf16* kh = KhS + ((jt + 1) << 12);
            const bf16* kl = KlS + ((jt + 1) << 12);
            const bf16* vs = VS + ((jt + 1) << 6);
            gll16(kh,        B);
            gll16(kh + 512,  B + 1024);
            gll16(kl,        B + 8192);
            gll16(kl + 512,  B + 8192 + 1024);
            gll16(vs,        B + 16384);
            gll16(vs + 8192, B + 16384 + 1024);
            asm volatile("s_waitcnt vmcnt(6)" ::: "memory");
        } else {
            asm volatile("s_waitcnt vmcnt(0)" ::: "memory");
        }
        __builtin_amdgcn_s_barrier();
        __builtin_amdgcn_sched_barrier(0);

        char* buf = lds + 24576 * p;

        f32x4 S[4];
#pragma unroll
        for (int m = 0; m < 4; ++m) {
            f32x4 acc = {0.f, 0.f, 0.f, 0.f};
#pragma unroll
            for (int ks = 0; ks < 2; ++ks) {
                const int row = lq + 16 * m;
                const int ch  = ((lg + 4 * ks) ^ (row & 7)) << 4;
                bf16x8 kh = *(const bf16x8*)(buf + row * 128 + ch);
                bf16x8 kl = *(const bf16x8*)(buf + 8192 + row * 128 + ch);
                __builtin_amdgcn_s_setprio(1);
                acc = MFMA16(kh, qh[ks], acc);
                acc = MFMA16(kh, qlo[ks], acc);
                acc = MFMA16(kl, qh[ks], acc);
                __builtin_amdgcn_s_setprio(0);
            }
            S[m] = acc;
        }

        float tm = S[0][0];
#pragma unroll
        for (int m = 0; m < 4; ++m)
#pragma unroll
            for (int r = 0; r < 4; ++r) tm = fmaxf(tm, S[m][r]);
        tm = fmaxf(tm, __shfl_xor(tm, 16));
        tm = fmaxf(tm, __shfl_xor(tm, 32));
        const float mnew = fmaxf(m_run, tm);
        const float corr = __expf(m_run - mnew);
        float ps[4][4];
        float psum = 0.f;
#pragma unroll
        for (int m = 0; m < 4; ++m)
#pragma unroll
            for (int r = 0; r < 4; ++r) {
                const float p2 = __expf(S[m][r] - mnew);
                ps[m][r] = p2;
                psum += p2;
            }
        psum += __shfl_xor(psum, 16);
        psum += __shfl_xor(psum, 32);
        l_run = l_run * corr + psum;
        m_run = mnew;
#pragma unroll
        for (int m = 0; m < 4; ++m)
#pragma unroll
            for (int r = 0; r < 4; ++r) Oa[m][r] *= corr;

#pragma unroll
        for (int f = 0; f < 4; ++f) {
            union { bf16 hh[4]; uint2 u; } pu;
            pu.hh[0] = (bf16)ps[f][0];
            pu.hh[1] = (bf16)ps[f][1];
            pu.hh[2] = (bf16)ps[f][2];
            pu.hh[3] = (bf16)ps[f][3];
            *(uint2*)(Pw + lq * 128 + (((2 * f + (lg >> 1)) ^ (lq & 7)) << 4) + ((lg & 1) << 3)) = pu.u;
        }

#pragma unroll
        for (int ks = 0; ks < 2; ++ks) {
            bf16x8 pb = *(const bf16x8*)(Pw + lq * 128 + (((lg + 4 * ks) ^ (lq & 7)) << 4));
            __builtin_amdgcn_s_setprio(1);
#pragma unroll
            for (int m = 0; m < 4; ++m) {
                const int row = lq + 16 * m;
                bf16x8 va = *(const bf16x8*)(buf + 16384 + row * 128 + (((lg + 4 * ks) ^ (row & 7)) << 4));
                Oa[m] = MFMA16(va, pb, Oa[m]);
            }
            __builtin_amdgcn_s_setprio(0);
        }

        asm volatile("s_waitcnt lgkmcnt(0)" ::: "memory");
        __builtin_amdgcn_s_barrier();
        __builtin_amdgcn_sched_barrier(0);
    }

    const float inv = 1.0f / l_run;
    const int i = i0 + w * 16 + lq;
    const size_t obase = ((size_t)(b * NN) + i) * HID + h * DDIM;
#pragma unroll
    for (int m = 0; m < 4; ++m) {
        bf16x4 ov;
#pragma unroll
        for (int r = 0; r < 4; ++r) ov[r] = (bf16)(Oa[m][r] * inv);
        *(bf16x4*)(Ot + obase + 16 * m + 4 * lg) = ov;
    }
}

// ---------------------------------------------------------------------------
extern "C" void kernel_launch(void* const* d_in, const int* in_sizes, int n_in,
                              void* d_out, int out_size, void* d_ws, size_t ws_size,
                              hipStream_t stream)
{
    const float* x_q   = (const float*)d_in[0];
    const float* x_kv  = (const float*)d_in[1];
    const float* w_q   = (const float*)d_in[2];
    const float* w_kv  = (const float*)d_in[3];
    const float* w_out = (const float*)d_in[4];
    float* out = (float*)d_out;

    char* ws = (char*)d_ws;
    bf16* Xtq   = (bf16*)(ws + 0);
    bf16* Ot    = (bf16*)(ws + 0);
    bf16* Xtkv  = (bf16*)(ws + 5242880);
    bf16* Wqh   = (bf16*)(ws + 15728640);
    bf16* Wql   = (bf16*)(ws + 16056320);
    bf16* Wkvh  = (bf16*)(ws + 16384000);
    bf16* Wkvl  = (bf16*)(ws + 17694720);
    bf16* Wouth = (bf16*)(ws + 19005440);
    bf16* Woutl = (bf16*)(ws + 19398656);
    bf16* Qhi   = (bf16*)(ws + 19791872);
    bf16* Qlo   = (bf16*)(ws + 28180480);
    bf16* Khi   = (bf16*)(ws + 36569088);
    bf16* Klo   = (bf16*)(ws + 44957696);
    bf16* Vt    = (bf16*)(ws + 53346304);

    dim3 blk(256);
    prep_kernel<<<dim3(2912), blk, 0, stream>>>(x_q, x_kv, w_q, w_kv, w_out,
                                                Xtq, Xtkv, Wqh, Wql, Wkvh, Wkvl,
                                                Wouth, Woutl);
    gemm_qkv_kernel<<<dim3(768), blk, 0, stream>>>(Xtq, Xtkv, Wqh, Wql, Wkvh, Wkvl,
                                                   Qhi, Qlo, Khi, Klo, Vt);
    attn_kernel<<<dim3(1024), blk, 0, stream>>>(Qhi, Qlo, Khi, Klo, Vt, Ot);
    outproj_kernel<<<dim3(3, 8, 8), blk, 0, stream>>>(Ot, Wouth, Woutl, out);
}

// Round 8
// 105.352 us; speedup vs baseline: 4.8311x; 1.1340x over previous
//
#include <hip/hip_runtime.h>
#include <math.h>

#define BB   8
#define HH   8
#define DDIM 64
#define NN   1024
#define HID  512
#define COUT 320

typedef float4 f4;
typedef __bf16 bf16;
typedef __attribute__((ext_vector_type(8))) __bf16 bf16x8;
typedef __attribute__((ext_vector_type(4))) __bf16 bf16x4;
typedef __attribute__((ext_vector_type(4))) float f32x4;

#define MFMA16(a,b,c) __builtin_amdgcn_mfma_f32_16x16x32_bf16((a),(b),(c),0,0,0)

__device__ __forceinline__ void gll16(const bf16* g, char* l) {
    __builtin_amdgcn_global_load_lds(
        (const __attribute__((address_space(1))) void*)g,
        (__attribute__((address_space(3))) void*)l, 16, 0, 0);
}

// ---------------------------------------------------------------------------
// Prep bodies (verified rounds 3-7)
// ---------------------------------------------------------------------------
template<int CIN>
__device__ __forceinline__
void conv_w_body(const float* __restrict__ W, bf16* __restrict__ Wh,
                 bf16* __restrict__ Wl, int rows_valid, int bx)
{
    const int idx = bx * 256 + threadIdx.x;
    const int row = idx / (CIN / 4);
    const int c4  = (idx % (CIN / 4)) * 4;
    f4 v = {0.f, 0.f, 0.f, 0.f};
    if (row < rows_valid) v = *(const f4*)&W[(size_t)row * CIN + c4];
    const float vv[4] = {v.x, v.y, v.z, v.w};
    bf16x4 hv, lv;
#pragma unroll
    for (int e = 0; e < 4; ++e) {
        bf16 hb = (bf16)vv[e];
        hv[e] = hb;
        lv[e] = (bf16)(vv[e] - (float)hb);
    }
    *(bf16x4*)&Wh[(size_t)row * CIN + c4] = hv;
    *(bf16x4*)&Wl[(size_t)row * CIN + c4] = lv;
}

template<int CIN>
__device__ __forceinline__
void conv_xt_body(const float* __restrict__ X, bf16* __restrict__ Xt,
                  float (*Xs)[68], int bx, int by, int bz)
{
    const int n0 = bx * 64;
    const int c0 = by * 64;
    const int t  = threadIdx.x;
    const float* Xb = X + (size_t)bz * CIN * NN;
#pragma unroll
    for (int it = 0; it < 4; ++it) {
        const int r  = it * 16 + (t >> 4);
        const int cc = (t & 15) * 4;
        *(f4*)&Xs[r][cc] = *(const f4*)&Xb[(size_t)(c0 + r) * NN + n0 + cc];
    }
    __syncthreads();
    const int n  = t >> 2;
    const int cb = (t & 3) * 16;
    union { bf16 h[16]; uint4 u[2]; } o;
#pragma unroll
    for (int e = 0; e < 16; ++e) o.h[e] = (bf16)Xs[cb + e][n];
    bf16* dst = Xt + ((size_t)bz * NN + n0 + n) * CIN + c0 + cb;
    *(uint4*)dst = o.u[0];
    *(uint4*)(dst + 8) = o.u[1];
}

__global__ __launch_bounds__(256)
void prep_kernel(const float* __restrict__ x_q, const float* __restrict__ x_kv,
                 const float* __restrict__ w_q, const float* __restrict__ w_kv,
                 const float* __restrict__ w_out,
                 bf16* __restrict__ Xtq, bf16* __restrict__ Xtkv,
                 bf16* __restrict__ Wqh, bf16* __restrict__ Wql,
                 bf16* __restrict__ Wkvh, bf16* __restrict__ Wkvl,
                 bf16* __restrict__ Wouth, bf16* __restrict__ Woutl)
{
    __shared__ __align__(16) float Xs[64][68];
    const int id = blockIdx.x;
    if (id < 640) {
        const int r = id >> 4;
        conv_xt_body<320>(x_q, Xtq, Xs, id & 15, r % 5, r / 5);
    } else if (id < 1920) {
        const int i = id - 640, r = i >> 4;
        conv_xt_body<640>(x_kv, Xtkv, Xs, i & 15, r % 10, r / 10);
    } else if (id < 2080) {
        conv_w_body<320>(w_q, Wqh, Wql, 512, id - 1920);
    } else if (id < 2720) {
        conv_w_body<640>(w_kv, Wkvh, Wkvl, 1024, id - 2080);
    } else {
        conv_w_body<512>(w_out, Wouth, Woutl, 320, id - 2720);
    }
}

// ---------------------------------------------------------------------------
// 2-term split-bf16 MFMA GEMM body (verified round 7): global_load_lds
// staging, double-buffered LDS, counted vmcnt(6) 2-phase pipeline.
// EPI 0/1: split hi/lo stores (Q). EPI 4: hi-only store (K, round 8).
// EPI 2: Vt. EPI 3: f32 out.
// ---------------------------------------------------------------------------
template<int K, int ASPLIT, int EPI>
__device__ __forceinline__
void gemm_body(char* lds,
               const bf16* __restrict__ Ah, const bf16* __restrict__ Al,
               const bf16* __restrict__ Bh, const bf16* __restrict__ Bl,
               long a_bstride, long b_bstride,
               bf16* __restrict__ D0, bf16* __restrict__ D1,
               float* __restrict__ Df, float scale,
               int bx, int by, int bz)
{
    const int t  = threadIdx.x;
    const int w  = t >> 6, l = t & 63;
    const int lg = l >> 4, lq = l & 15;
    const int wa = w >> 1, wb = w & 1;
    const int arow0 = by * 128;
    const int brow0 = bx * 128;

    const bf16* Ab = Ah + (size_t)bz * a_bstride;
    const bf16* Xb = ASPLIT ? (Al + (size_t)bz * a_bstride)
                            : (Bl + (size_t)bz * b_bstride);
    const bf16* Bb = Bh + (size_t)bz * b_bstride;

    const int srow = 16 * w + (l >> 2);
    const int cw   = (l & 3) ^ ((l >> 3) & 3);
    const bf16* pA = Ab + (size_t)(arow0 + srow) * K + cw * 8;
    const bf16* pX = Xb + (size_t)((ASPLIT ? arow0 : brow0) + srow) * K + cw * 8;
    const bf16* pB = Bb + (size_t)(brow0 + srow) * K + cw * 8;
    const int woff = w * 1024;

    f32x4 acc[4][4];
#pragma unroll
    for (int i = 0; i < 4; ++i)
#pragma unroll
        for (int j = 0; j < 4; ++j) acc[i][j] = (f32x4){0.f, 0.f, 0.f, 0.f};

    constexpr int NK = K / 32;

#define GEMM_ISSUE(ks, pbuf)                                          \
    {                                                                 \
        char* Bd = lds + (pbuf) * 24576 + woff;                       \
        const int ko = (ks) * 32;                                     \
        gll16(pA + ko,          Bd);                                  \
        gll16(pA + 64 * K + ko, Bd + 4096);                           \
        gll16(pX + ko,          Bd + 8192);                           \
        gll16(pX + 64 * K + ko, Bd + 8192 + 4096);                    \
        gll16(pB + ko,          Bd + 16384);                          \
        gll16(pB + 64 * K + ko, Bd + 16384 + 4096);                   \
    }

    GEMM_ISSUE(0, 0)

    for (int ks = 0; ks < NK; ++ks) {
        const int p = ks & 1;
        if (ks + 1 < NK) {
            GEMM_ISSUE(ks + 1, p ^ 1)
            asm volatile("s_waitcnt vmcnt(6)" ::: "memory");
        } else {
            asm volatile("s_waitcnt vmcnt(0)" ::: "memory");
        }
        __builtin_amdgcn_s_barrier();
        __builtin_amdgcn_sched_barrier(0);

        char* buf = lds + p * 24576;
        bf16x8 a0[4], a1[4], b0[4], b1[4];
#pragma unroll
        for (int m = 0; m < 4; ++m) {
            const int rA = wa * 64 + 16 * m + lq;
            const int offA = rA * 64 + ((lg ^ ((rA >> 1) & 3)) << 4);
            a0[m] = *(const bf16x8*)(buf + offA);
            if (ASPLIT) a1[m] = *(const bf16x8*)(buf + 8192 + offA);
            const int rB = wb * 64 + 16 * m + lq;
            const int offB = rB * 64 + ((lg ^ ((rB >> 1) & 3)) << 4);
            b0[m] = *(const bf16x8*)(buf + 16384 + offB);
            if (!ASPLIT) b1[m] = *(const bf16x8*)(buf + 8192 + offB);
        }
        __builtin_amdgcn_s_setprio(1);
#pragma unroll
        for (int mA = 0; mA < 4; ++mA)
#pragma unroll
            for (int mB = 0; mB < 4; ++mB) {
                acc[mA][mB] = MFMA16(a0[mA], b0[mB], acc[mA][mB]);
                acc[mA][mB] = ASPLIT ? MFMA16(a1[mA], b0[mB], acc[mA][mB])
                                     : MFMA16(a0[mA], b1[mB], acc[mA][mB]);
            }
        __builtin_amdgcn_s_setprio(0);
        asm volatile("s_waitcnt lgkmcnt(0)" ::: "memory");
        __builtin_amdgcn_s_barrier();
        __builtin_amdgcn_sched_barrier(0);
    }
#undef GEMM_ISSUE

#pragma unroll
    for (int mA = 0; mA < 4; ++mA)
#pragma unroll
        for (int mB = 0; mB < 4; ++mB) {
            if (EPI <= 1 || EPI == 4) {
                const int o = arow0 + wa * 64 + 16 * mA + 4 * lg;
                const int i = brow0 + wb * 64 + 16 * mB + lq;
                const int h = o >> 6, d = o & 63;
                const size_t base = ((size_t)((bz * HH + h) * NN + i)) * 64 + d;
                bf16x4 hv, lv;
#pragma unroll
                for (int r = 0; r < 4; ++r) {
                    const float v = acc[mA][mB][r] * scale;
                    bf16 hb = (bf16)v;
                    hv[r] = hb;
                    lv[r] = (bf16)(v - (float)hb);
                }
                *(bf16x4*)(D0 + base) = hv;
                if (EPI <= 1) *(bf16x4*)(D1 + base) = lv;
            } else if (EPI == 2) {
                const int i = arow0 + wa * 64 + 16 * mA + 4 * lg;
                const int o = brow0 + wb * 64 + 16 * mB + lq;
                const int h = o >> 6, d = o & 63;
                const size_t base = ((size_t)((bz * HH + h) * DDIM + d)) * NN + i;
                bf16x4 pv;
#pragma unroll
                for (int r = 0; r < 4; ++r) pv[r] = (bf16)acc[mA][mB][r];
                *(bf16x4*)(D0 + base) = pv;
            } else {
                const int i = arow0 + wa * 64 + 16 * mA + 4 * lg;
                const int o = brow0 + wb * 64 + 16 * mB + lq;
                if (o < COUT)
                    *(f32x4*)(Df + ((size_t)(bz * COUT + o)) * NN + i) = acc[mA][mB];
            }
        }
}

__global__ __launch_bounds__(256, 2)
void gemm_qkv_kernel(const bf16* __restrict__ Xtq, const bf16* __restrict__ Xtkv,
                     const bf16* __restrict__ Wqh, const bf16* __restrict__ Wql,
                     const bf16* __restrict__ Wkvh, const bf16* __restrict__ Wkvl,
                     bf16* __restrict__ Qhi, bf16* __restrict__ Qlo,
                     bf16* __restrict__ Khi, bf16* __restrict__ Vt)
{
    __shared__ __align__(16) char lds[49152];
    const int id = blockIdx.x;
    if (id < 256) {
        gemm_body<320, 1, 0>(lds, Wqh, Wql, Xtq, nullptr, 0, (long)NN * 320,
                             Qhi, Qlo, nullptr, 0.125f,
                             id & 7, (id >> 3) & 3, id >> 5);
    } else if (id < 512) {
        const int i = id - 256;
        gemm_body<640, 1, 4>(lds, Wkvh, Wkvl, Xtkv, nullptr, 0, (long)NN * 640,
                             Khi, nullptr, nullptr, 1.0f,
                             i & 7, (i >> 3) & 3, i >> 5);
    } else {
        const int i = id - 512;
        gemm_body<640, 0, 2>(lds, Xtkv, nullptr,
                             Wkvh + (size_t)HID * 640, Wkvl + (size_t)HID * 640,
                             (long)NN * 640, 0, Vt, nullptr, nullptr, 1.0f,
                             i & 3, (i >> 2) & 7, i >> 5);
    }
}

__global__ __launch_bounds__(256, 2)
void outproj_kernel(const bf16* __restrict__ Ot,
                    const bf16* __restrict__ Wouth, const bf16* __restrict__ Woutl,
                    float* __restrict__ out)
{
    __shared__ __align__(16) char lds[49152];
    gemm_body<512, 0, 3>(lds, Ot, nullptr, Wouth, Woutl, (long)NN * HID, 0,
                         nullptr, nullptr, out, 1.0f,
                         blockIdx.x, blockIdx.y, blockIdx.z);
}

// ---------------------------------------------------------------------------
// MFMA flash attention, round 8: 2-term QK^T (kh*qh + kh*ql; kl term dropped)
// -> K-lo eliminated from staging; LDS 2x16KB dbuf + 8KB P = 40960 B ->
// 4 blocks/CU (16 waves/CU, was 8). 4 x gll16 per tile, counted vmcnt(4).
// ---------------------------------------------------------------------------
__global__ __launch_bounds__(256, 4)
void attn_kernel(const bf16* __restrict__ Qhi, const bf16* __restrict__ Qlo,
                 const bf16* __restrict__ Khi, const bf16* __restrict__ Vt,
                 bf16* __restrict__ Ot)
{
    const int id  = blockIdx.x;
    const int loc = id >> 3;
    const int bh  = (id & 7) * 8 + (loc >> 4);   // 8 bh per XCD
    const int i0  = (loc & 15) * 64;
    const int b   = bh >> 3, h = bh & 7;
    const int t   = threadIdx.x;
    const int w   = t >> 6;
    const int l   = t & 63;
    const int lg  = l >> 4;
    const int lq  = l & 15;

    __shared__ __align__(16) char lds[40960];
    // [0,16384) buf0 {Khi 8K, V 8K}; [16384,32768) buf1; [32768,40960) P

    const size_t qbase = ((size_t)(bh * NN) + i0 + w * 16 + lq) * DDIM + lg * 8;
    bf16x8 qh[2], qlo[2];
    qh[0]  = *(const bf16x8*)(Qhi + qbase);
    qh[1]  = *(const bf16x8*)(Qhi + qbase + 32);
    qlo[0] = *(const bf16x8*)(Qlo + qbase);
    qlo[1] = *(const bf16x8*)(Qlo + qbase + 32);

    const int l8 = l >> 3;
    const int cw = (l & 7) ^ l8;
    const bf16* KhS = Khi + ((size_t)(bh * NN) + 16 * w + l8) * DDIM + cw * 8;
    const bf16* VS  = Vt  + (((size_t)(bh * DDIM) + 16 * w + l8) << 10) + cw * 8;
    char* const Lw = lds + (w << 11);

    f32x4 Oa[4];
#pragma unroll
    for (int m = 0; m < 4; ++m) { Oa[m][0]=0.f; Oa[m][1]=0.f; Oa[m][2]=0.f; Oa[m][3]=0.f; }
    float m_run = -INFINITY, l_run = 0.f;

    char* Pw = lds + 32768 + w * 2048;

    {
        gll16(KhS,        Lw);
        gll16(KhS + 512,  Lw + 1024);
        gll16(VS,         Lw + 8192);
        gll16(VS + 8192,  Lw + 8192 + 1024);
    }

    for (int jt = 0; jt < 16; ++jt) {
        const int p = jt & 1;
        if (jt < 15) {
            char* B = Lw + 16384 * (p ^ 1);
            const bf16* kh = KhS + ((jt + 1) << 12);
            const bf16* vs = VS + ((jt + 1) << 6);
            gll16(kh,        B);
            gll16(kh + 512,  B + 1024);
            gll16(vs,        B + 8192);
            gll16(vs + 8192, B + 8192 + 1024);
            asm volatile("s_waitcnt vmcnt(4)" ::: "memory");
        } else {
            asm volatile("s_waitcnt vmcnt(0)" ::: "memory");
        }
        __builtin_amdgcn_s_barrier();
        __builtin_amdgcn_sched_barrier(0);

        char* buf = lds + 16384 * p;

        // ---- St = K·Q^T (rows j, cols q); 2-term ----
        f32x4 S[4];
#pragma unroll
        for (int m = 0; m < 4; ++m) {
            f32x4 acc = {0.f, 0.f, 0.f, 0.f};
#pragma unroll
            for (int ks = 0; ks < 2; ++ks) {
                const int row = lq + 16 * m;
                const int ch  = ((lg + 4 * ks) ^ (row & 7)) << 4;
                bf16x8 kh = *(const bf16x8*)(buf + row * 128 + ch);
                __builtin_amdgcn_s_setprio(1);
                acc = MFMA16(kh, qh[ks], acc);
                acc = MFMA16(kh, qlo[ks], acc);
                __builtin_amdgcn_s_setprio(0);
            }
            S[m] = acc;
        }

        // ---- online softmax: lane holds 16 j's for q = lq ----
        float tm = S[0][0];
#pragma unroll
        for (int m = 0; m < 4; ++m)
#pragma unroll
            for (int r = 0; r < 4; ++r) tm = fmaxf(tm, S[m][r]);
        tm = fmaxf(tm, __shfl_xor(tm, 16));
        tm = fmaxf(tm, __shfl_xor(tm, 32));
        const float mnew = fmaxf(m_run, tm);
        const float corr = __expf(m_run - mnew);
        float ps[4][4];
        float psum = 0.f;
#pragma unroll
        for (int m = 0; m < 4; ++m)
#pragma unroll
            for (int r = 0; r < 4; ++r) {
                const float p2 = __expf(S[m][r] - mnew);
                ps[m][r] = p2;
                psum += p2;
            }
        psum += __shfl_xor(psum, 16);
        psum += __shfl_xor(psum, 32);
        l_run = l_run * corr + psum;
        m_run = mnew;
#pragma unroll
        for (int m = 0; m < 4; ++m)
#pragma unroll
            for (int r = 0; r < 4; ++r) Oa[m][r] *= corr;

        // ---- P -> per-wave LDS (bf16) ----
#pragma unroll
        for (int f = 0; f < 4; ++f) {
            union { bf16 hh[4]; uint2 u; } pu;
            pu.hh[0] = (bf16)ps[f][0];
            pu.hh[1] = (bf16)ps[f][1];
            pu.hh[2] = (bf16)ps[f][2];
            pu.hh[3] = (bf16)ps[f][3];
            *(uint2*)(Pw + lq * 128 + (((2 * f + (lg >> 1)) ^ (lq & 7)) << 4) + ((lg & 1) << 3)) = pu.u;
        }

        // ---- Ot += Vt · Pt ----
#pragma unroll
        for (int ks = 0; ks < 2; ++ks) {
            bf16x8 pb = *(const bf16x8*)(Pw + lq * 128 + (((lg + 4 * ks) ^ (lq & 7)) << 4));
            __builtin_amdgcn_s_setprio(1);
#pragma unroll
            for (int m = 0; m < 4; ++m) {
                const int row = lq + 16 * m;
                bf16x8 va = *(const bf16x8*)(buf + 8192 + row * 128 + (((lg + 4 * ks) ^ (row & 7)) << 4));
                Oa[m] = MFMA16(va, pb, Oa[m]);
            }
            __builtin_amdgcn_s_setprio(0);
        }

        asm volatile("s_waitcnt lgkmcnt(0)" ::: "memory");
        __builtin_amdgcn_s_barrier();
        __builtin_amdgcn_sched_barrier(0);
    }

    const float inv = 1.0f / l_run;
    const int i = i0 + w * 16 + lq;
    const size_t obase = ((size_t)(b * NN) + i) * HID + h * DDIM;
#pragma unroll
    for (int m = 0; m < 4; ++m) {
        bf16x4 ov;
#pragma unroll
        for (int r = 0; r < 4; ++r) ov[r] = (bf16)(Oa[m][r] * inv);
        *(bf16x4*)(Ot + obase + 16 * m + 4 * lg) = ov;
    }
}

// ---------------------------------------------------------------------------
extern "C" void kernel_launch(void* const* d_in, const int* in_sizes, int n_in,
                              void* d_out, int out_size, void* d_ws, size_t ws_size,
                              hipStream_t stream)
{
    const float* x_q   = (const float*)d_in[0];
    const float* x_kv  = (const float*)d_in[1];
    const float* w_q   = (const float*)d_in[2];
    const float* w_kv  = (const float*)d_in[3];
    const float* w_out = (const float*)d_in[4];
    float* out = (float*)d_out;

    char* ws = (char*)d_ws;
    bf16* Xtq   = (bf16*)(ws + 0);
    bf16* Ot    = (bf16*)(ws + 0);
    bf16* Xtkv  = (bf16*)(ws + 5242880);
    bf16* Wqh   = (bf16*)(ws + 15728640);
    bf16* Wql   = (bf16*)(ws + 16056320);
    bf16* Wkvh  = (bf16*)(ws + 16384000);
    bf16* Wkvl  = (bf16*)(ws + 17694720);
    bf16* Wouth = (bf16*)(ws + 19005440);
    bf16* Woutl = (bf16*)(ws + 19398656);
    bf16* Qhi   = (bf16*)(ws + 19791872);
    bf16* Qlo   = (bf16*)(ws + 28180480);
    bf16* Khi   = (bf16*)(ws + 36569088);
    bf16* Vt    = (bf16*)(ws + 53346304);

    dim3 blk(256);
    prep_kernel<<<dim3(2912), blk, 0, stream>>>(x_q, x_kv, w_q, w_kv, w_out,
                                                Xtq, Xtkv, Wqh, Wql, Wkvh, Wkvl,
                                                Wouth, Woutl);
    gemm_qkv_kernel<<<dim3(768), blk, 0, stream>>>(Xtq, Xtkv, Wqh, Wql, Wkvh, Wkvl,
                                                   Qhi, Qlo, Khi, Vt);
    attn_kernel<<<dim3(1024), blk, 0, stream>>>(Qhi, Qlo, Khi, Vt, Ot);
    outproj_kernel<<<dim3(3, 8, 8), blk, 0, stream>>>(Ot, Wouth, Woutl, out);
}